// Round 17
// baseline (126.384 us; speedup 1.0000x reference)
//
#include <hip/hip_runtime.h>

#define B_  2
#define Q_  2048
#define KV_ 2048
#define D_  1024
#define H_  16
#define DH_ 64

// 0.125 * log2(e): folded into qp so attention scores feed exp2 directly
#define QSCALE 0.18033688011112042f

using u16 = unsigned short;
using bf16x8 = __attribute__((ext_vector_type(8))) short;
using f32x4  = __attribute__((ext_vector_type(4))) float;

__device__ __forceinline__ u16 f2bf(float x) {
  unsigned u = __float_as_uint(x);
  u += 0x7fffu + ((u >> 16) & 1u);   // round-to-nearest-even
  return (u16)(u >> 16);
}

__device__ __forceinline__ void gl_lds16(const void* g, void* l) {
  __builtin_amdgcn_global_load_lds(
      (const __attribute__((address_space(1))) void*)g,
      (__attribute__((address_space(3))) void*)l, 16, 0, 0);
}

// Counted vmcnt wait. static_assert: an uncovered N must be a COMPILE error
// (round-14 lesson: a silent fall-through = no wait = LDS race).
template<int N> __device__ __forceinline__ void wait_vmcnt() {
  static_assert(N == 0 || N == 1 || N == 2 || N == 3 || N == 4 ||
                N == 6 || N == 8, "wait_vmcnt: unsupported N");
  if constexpr (N == 0)      asm volatile("s_waitcnt vmcnt(0)" ::: "memory");
  else if constexpr (N == 1) asm volatile("s_waitcnt vmcnt(1)" ::: "memory");
  else if constexpr (N == 2) asm volatile("s_waitcnt vmcnt(2)" ::: "memory");
  else if constexpr (N == 3) asm volatile("s_waitcnt vmcnt(3)" ::: "memory");
  else if constexpr (N == 4) asm volatile("s_waitcnt vmcnt(4)" ::: "memory");
  else if constexpr (N == 6) asm volatile("s_waitcnt vmcnt(6)" ::: "memory");
  else if constexpr (N == 8) asm volatile("s_waitcnt vmcnt(8)" ::: "memory");
}
__device__ __forceinline__ void barrier_raw() {
  asm volatile("" ::: "memory");
  __builtin_amdgcn_s_barrier();
  asm volatile("" ::: "memory");
}

#define MFMA16(a, b, c) __builtin_amdgcn_mfma_f32_16x16x32_bf16((a), (b), (c), 0, 0, 0)
#define EXP2F(x) __builtin_amdgcn_exp2f(x)

// ---------------------------------------------------------------------------
// Kernel 1 (merged prep), grid 4097 (round-13 form)
// ---------------------------------------------------------------------------
__global__ __launch_bounds__(256) void k_prep(
    const float* __restrict__ q, const float* __restrict__ k,
    const float* __restrict__ wq, const float* __restrict__ wk,
    const float* __restrict__ Wq, const float* __restrict__ Wk,
    const float* __restrict__ bq, const float* __restrict__ bk,
    const float* __restrict__ v,
    u16* __restrict__ qn, u16* __restrict__ kn,
    u16* __restrict__ Wb, float* __restrict__ biasbuf,
    u16* __restrict__ vT)
{
  __shared__ char smem[64 * 72 * 2];
  const int bid = blockIdx.x, t = threadIdx.x;
  if (bid < 2048) {
    const int w = t >> 6, lane = t & 63;
    const int row = bid * 4 + w;
    const float* src; const float* wgt; u16* dst;
    if (row < B_ * Q_) {
      src = q + (size_t)row * D_; wgt = wq; dst = qn + (size_t)row * D_;
    } else {
      const int r2 = row - B_ * Q_;
      src = k + (size_t)r2 * D_; wgt = wk; dst = kn + (size_t)r2 * D_;
    }
    float4 v4[4];
    float ss = 0.f;
    #pragma unroll
    for (int i = 0; i < 4; ++i) {
      v4[i] = reinterpret_cast<const float4*>(src)[lane + 64 * i];
      ss += v4[i].x * v4[i].x + v4[i].y * v4[i].y
          + v4[i].z * v4[i].z + v4[i].w * v4[i].w;
    }
    #pragma unroll
    for (int off = 1; off < 64; off <<= 1) ss += __shfl_xor(ss, off);
    const float sc = rsqrtf(ss * (1.0f / D_) + 1.1920929e-07f);
    #pragma unroll
    for (int i = 0; i < 4; ++i) {
      const float4 wv = reinterpret_cast<const float4*>(wgt)[lane + 64 * i];
      ushort4 o;
      o.x = f2bf(v4[i].x * sc * wv.x);
      o.y = f2bf(v4[i].y * sc * wv.y);
      o.z = f2bf(v4[i].z * sc * wv.z);
      o.w = f2bf(v4[i].w * sc * wv.w);
      reinterpret_cast<ushort4*>(dst)[lane + 64 * i] = o;
    }
  } else if (bid < 3072) {
    const int pb = bid - 2048;
    #pragma unroll
    for (int rr = 0; rr < 2; ++rr) {
      const int i = pb * 512 + rr * 256 + t;
      const bool isK = i >= 262144;
      const int j = i & 262143;
      float4 vv = reinterpret_cast<const float4*>(isK ? Wk : Wq)[j];
      ushort4 o;
      o.x = f2bf(vv.x); o.y = f2bf(vv.y); o.z = f2bf(vv.z); o.w = f2bf(vv.w);
      reinterpret_cast<ushort4*>(Wb + (isK ? D_ * D_ : 0))[j] = o;
    }
  } else if (bid == 3072) {
    #pragma unroll
    for (int rr = 0; rr < 2; ++rr) {
      const int i = rr * 256 + t;
      float4 vv = (i < 256) ? reinterpret_cast<const float4*>(bq)[i]
                            : reinterpret_cast<const float4*>(bk)[i - 256];
      reinterpret_cast<float4*>(biasbuf)[i] = vv;
    }
  } else {
    const int tb = bid - 3073;
    const int kv0 = (tb & 31) * 64, d0 = ((tb >> 5) & 15) * 64, b = tb >> 9;
    u16 (*tile)[72] = (u16(*)[72])smem;
    #pragma unroll
    for (int i = 0; i < 16; ++i) {
      const int idx = i * 256 + t, r = idx >> 6, c = idx & 63;
      tile[r][c] = f2bf(v[((size_t)b * KV_ + kv0 + r) * D_ + d0 + c]);
    }
    __syncthreads();
    #pragma unroll
    for (int i = 0; i < 16; ++i) {
      const int idx = i * 256 + t, r = idx >> 6, c = idx & 63;
      vT[((size_t)b * D_ + d0 + r) * KV_ + kv0 + c] = tile[c][r];
    }
  }
}

// ---------------------------------------------------------------------------
// Kernel 4: C = A * B^T (+bias,*scale), bf16 in, fp32 accum. TM x TN tile,
// BK=64, 512 threads = 8 waves WM x WN, T2-swizzled LDS, 2-deep dbuf +
// counted-vmcnt pipeline. (round-13 form; used by the projections)
// ---------------------------------------------------------------------------
template<int TM, int TN, int WM, int WN, bool OUT_BF16, bool PROJ>
__global__ __launch_bounds__(512) void k_gemm_bt(
    const u16* __restrict__ A, int lda, long sA,
    const u16* __restrict__ Bm, int ldb, long sB,
    void* __restrict__ C, int ldc, long sC,
    int K, const float* __restrict__ bias)
{
  constexpr int RM = TM / WM / 16, RN = TN / WN / 16;
  constexpr int LA = TM / 64, LB = TN / 64;
  constexpr int NL = LA + LB;
  const int bb = blockIdx.z;
  const u16* Ab = A + (size_t)bb * sA;
  const u16* Bb = Bm + (size_t)bb * sB;
  const int row0 = blockIdx.y * TM, col0 = blockIdx.x * TN;
  __shared__ u16 As[2][TM * 64];
  __shared__ u16 Bs[2][TN * 64];
  const int tid = threadIdx.x, lane = tid & 63;
  const int w = tid >> 6, wm = w / WN, wn = w % WN;
  const int lrow = lane & 15, sub = lane >> 4, lrow7 = lrow & 7;
  const f32x4 zero4 = {0.f, 0.f, 0.f, 0.f};
  f32x4 acc[RM][RN];
  #pragma unroll
  for (int m = 0; m < RM; ++m)
    #pragma unroll
    for (int n = 0; n < RN; ++n) acc[m][n] = zero4;

  const int nk = K >> 6;

#define GEMM_STAGE(buf, kt)                                                   \
  {                                                                           \
    const int k0 = (kt) << 6;                                                 \
    _Pragma("unroll")                                                         \
    for (int i = 0; i < LA; ++i) {                                            \
      const int c = i * 512 + tid, r = c >> 3, u = (c & 7) ^ (r & 7);         \
      gl_lds16(Ab + (size_t)(row0 + r) * lda + k0 + u * 8, &As[buf][c * 8]);  \
    }                                                                         \
    _Pragma("unroll")                                                         \
    for (int i = 0; i < LB; ++i) {                                            \
      const int c = i * 512 + tid, r = c >> 3, u = (c & 7) ^ (r & 7);         \
      gl_lds16(Bb + (size_t)(col0 + r) * ldb + k0 + u * 8, &Bs[buf][c * 8]);  \
    }                                                                         \
  }

  GEMM_STAGE(0, 0);
  int cur = 0;
  for (int kt = 0; kt < nk; ++kt) {
    if (kt + 1 < nk) {
      GEMM_STAGE(cur ^ 1, kt + 1);
      wait_vmcnt<NL>();                  // previous stage done; next in flight
    } else {
      wait_vmcnt<0>();
    }
    barrier_raw();                       // buf[cur] visible to all waves
    #pragma unroll
    for (int ks = 0; ks < 2; ++ks) {
      bf16x8 af[RM], bfr[RN];
      #pragma unroll
      for (int m = 0; m < RM; ++m) {
        const int rA = wm * (TM / WM) + m * 16 + lrow;
        af[m] = *(const bf16x8*)&As[cur][rA * 64 + ((((ks << 2) + sub) ^ lrow7) << 3)];
      }
      #pragma unroll
      for (int n = 0; n < RN; ++n) {
        const int rB = wn * (TN / WN) + n * 16 + lrow;
        bfr[n] = *(const bf16x8*)&Bs[cur][rB * 64 + ((((ks << 2) + sub) ^ lrow7) << 3)];
      }
      #pragma unroll
      for (int m = 0; m < RM; ++m)
        #pragma unroll
        for (int n = 0; n < RN; ++n)
          acc[m][n] = MFMA16(af[m], bfr[n], acc[m][n]);
    }
    barrier_raw();                       // all waves done reading buf[cur]
    cur ^= 1;
  }
#undef GEMM_STAGE

  const int crow = sub * 4, ccol = lane & 15;
  const float scl = (PROJ && bb == 0) ? QSCALE : 1.0f;
  #pragma unroll
  for (int m = 0; m < RM; ++m) {
    #pragma unroll
    for (int n = 0; n < RN; ++n) {
      const int gcol = col0 + wn * (TN / WN) + n * 16 + ccol;
      const float badd = PROJ ? bias[bb * 1024 + gcol] : 0.0f;
      #pragma unroll
      for (int r = 0; r < 4; ++r) {
        const int grow = row0 + wm * (TM / WM) + m * 16 + crow + r;
        const float val = (acc[m][n][r] + badd) * scl;
        if (OUT_BF16)
          ((u16*)C)[(size_t)bb * sC + (size_t)grow * ldc + gcol] = f2bf(val);
        else
          ((float*)C)[(size_t)bb * sC + (size_t)grow * ldc + gcol] = val;
      }
    }
  }
}

// ---------------------------------------------------------------------------
// Kernel 4b: PV GEMM, 3-deep rotation, ONE barrier per K-step (round-16 form).
// ---------------------------------------------------------------------------
__global__ __launch_bounds__(512) void k_gemm_pv3(
    const u16* __restrict__ A, long sA,      // attn: Q x KV rows, lda=KV
    const u16* __restrict__ Bm, long sB,     // vT:   D x KV rows, ldb=KV
    float* __restrict__ C, long sC)          // out:  Q x D, fp32
{
  const int bb = blockIdx.z;
  const u16* Ab = A + (size_t)bb * sA;
  const u16* Bb = Bm + (size_t)bb * sB;
  const int row0 = blockIdx.y * 128, col0 = blockIdx.x * 64;
  __shared__ u16 As3[3][128 * 64];           // 48 KB
  __shared__ u16 Bs3[3][64 * 64];            // 24 KB
  const int tid = threadIdx.x, lane = tid & 63;
  const int w = tid >> 6, wm = w >> 1, wn = w & 1;   // 4M x 2N
  const int lrow = lane & 15, sub = lane >> 4, lrow7 = lrow & 7;
  const f32x4 zero4 = {0.f, 0.f, 0.f, 0.f};
  f32x4 acc[2][2];
  #pragma unroll
  for (int m = 0; m < 2; ++m)
    #pragma unroll
    for (int n = 0; n < 2; ++n) acc[m][n] = zero4;

  const int nk = KV_ >> 6;                   // 32 K-tiles

#define PV_STAGE(buf, kt)                                                     \
  {                                                                           \
    const int k0 = (kt) << 6;                                                 \
    _Pragma("unroll")                                                         \
    for (int i = 0; i < 2; ++i) {                                             \
      const int c = i * 512 + tid, r = c >> 3, u = (c & 7) ^ (r & 7);         \
      gl_lds16(Ab + (size_t)(row0 + r) * KV_ + k0 + u * 8, &As3[buf][c * 8]); \
    }                                                                         \
    {                                                                         \
      const int c = tid, r = c >> 3, u = (c & 7) ^ (r & 7);                   \
      gl_lds16(Bb + (size_t)(col0 + r) * KV_ + k0 + u * 8, &Bs3[buf][c * 8]); \
    }                                                                         \
  }

  PV_STAGE(0, 0);
  PV_STAGE(1, 1);
  for (int kt = 0; kt < nk; ++kt) {
    const int cb = kt % 3;
    if (kt + 1 < nk) wait_vmcnt<3>();        // tile kt landed; kt+1 in flight
    else             wait_vmcnt<0>();
    barrier_raw();                           // orders vs compute(kt-1) too
    if (kt + 2 < nk) PV_STAGE((kt + 2) % 3, kt + 2);
    #pragma unroll
    for (int ks = 0; ks < 2; ++ks) {
      bf16x8 af[2], bfr[2];
      #pragma unroll
      for (int m = 0; m < 2; ++m) {
        const int rA = wm * 32 + m * 16 + lrow;
        af[m] = *(const bf16x8*)&As3[cb][rA * 64 + ((((ks << 2) + sub) ^ lrow7) << 3)];
      }
      #pragma unroll
      for (int n = 0; n < 2; ++n) {
        const int rB = wn * 32 + n * 16 + lrow;
        bfr[n] = *(const bf16x8*)&Bs3[cb][rB * 64 + ((((ks << 2) + sub) ^ lrow7) << 3)];
      }
      #pragma unroll
      for (int m = 0; m < 2; ++m)
        #pragma unroll
        for (int n = 0; n < 2; ++n)
          acc[m][n] = MFMA16(af[m], bfr[n], acc[m][n]);
    }
  }
#undef PV_STAGE

  const int crow = sub * 4, ccol = lane & 15;
  #pragma unroll
  for (int m = 0; m < 2; ++m) {
    #pragma unroll
    for (int n = 0; n < 2; ++n) {
      const int gcol = col0 + wn * 32 + n * 16 + ccol;
      #pragma unroll
      for (int r = 0; r < 4; ++r) {
        const int grow = row0 + wm * 32 + m * 16 + crow + r;
        C[(size_t)bb * sC + (size_t)grow * D_ + gcol] = acc[m][n][r];
      }
    }
  }
}

// ---------------------------------------------------------------------------
// Kernel 5 (pass A, NEW 3-deep): Linv[b,h,i] = 1 / (H * sum_j 2^s(i,j))
// block = (128 q-rows, head, batch), 8 waves 2x4 (64q x 32kv). Aq staged
// once; K 128-tiles in 3-deep rotation, stage-after-barrier, ONE barrier
// per kv-tile (PV3 pattern). LDS 16+48+2=66 KB -> 2 blocks/CU retained.
// vmcnt(2): prologue leaves Aq+K0+K1=6 outstanding; wait to 2 at iter kt
// drains K_kt (and Aq at kt=0) while K_{kt+1} stays in flight.
// ---------------------------------------------------------------------------
__global__ __launch_bounds__(512) void k_attn_rowsum(
    const u16* __restrict__ qp, const u16* __restrict__ kp,
    float* __restrict__ Linv)
{
  const int qb = blockIdx.x * 128, h = blockIdx.y, b = blockIdx.z;
  __shared__ u16 Aq[128 * 64];
  __shared__ u16 Kk[3][128 * 64];
  __shared__ float red[4][128];
  const int tid = threadIdx.x, lane = tid & 63, w = tid >> 6;
  const int wm = w >> 2, wn = w & 3;
  const int lrow = lane & 15, sub = lane >> 4, lrow7 = lrow & 7;

  #pragma unroll
  for (int i = 0; i < 2; ++i) {
    const int c = i * 512 + tid, r = c >> 3, u = (c & 7) ^ (r & 7);
    gl_lds16(&qp[((size_t)b * Q_ + qb + r) * D_ + h * 64 + u * 8], &Aq[c * 8]);
  }

#define STAGE_KK(buf, kvt)                                                    \
  {                                                                           \
    _Pragma("unroll")                                                         \
    for (int i = 0; i < 2; ++i) {                                             \
      const int c = i * 512 + tid, r = c >> 3, u = (c & 7) ^ (r & 7);         \
      gl_lds16(&kp[((size_t)b * KV_ + (kvt) * 128 + r) * D_ + h * 64 + u * 8],\
               &Kk[buf][c * 8]);                                              \
    }                                                                         \
  }

  STAGE_KK(0, 0);
  STAGE_KK(1, 1);
  const f32x4 zero4 = {0.f, 0.f, 0.f, 0.f};
  float lsum[4][4];
  #pragma unroll
  for (int m = 0; m < 4; ++m)
    #pragma unroll
    for (int r = 0; r < 4; ++r) lsum[m][r] = 0.f;
  bf16x8 af[4][2];

  const int nkv = KV_ / 128;
  for (int kvt = 0; kvt < nkv; ++kvt) {
    const int cb = kvt % 3;
    if (kvt + 1 < nkv) wait_vmcnt<2>();
    else               wait_vmcnt<0>();
    barrier_raw();                       // K_kvt visible; orders vs cmp(kvt-1)
    if (kvt + 2 < nkv) STAGE_KK((kvt + 2) % 3, kvt + 2);
    if (kvt == 0) {
      #pragma unroll
      for (int m = 0; m < 4; ++m) {
        const int rA = wm * 64 + m * 16 + lrow;
        af[m][0] = *(const bf16x8*)&Aq[rA * 64 + ((sub ^ lrow7) << 3)];
        af[m][1] = *(const bf16x8*)&Aq[rA * 64 + (((4 + sub) ^ lrow7) << 3)];
      }
    }
    bf16x8 bf[2][2];
    #pragma unroll
    for (int n = 0; n < 2; ++n) {
      const int rB = wn * 32 + n * 16 + lrow;
      bf[n][0] = *(const bf16x8*)&Kk[cb][rB * 64 + ((sub ^ lrow7) << 3)];
      bf[n][1] = *(const bf16x8*)&Kk[cb][rB * 64 + (((4 + sub) ^ lrow7) << 3)];
    }
    __builtin_amdgcn_s_setprio(1);
    #pragma unroll
    for (int m = 0; m < 4; ++m) {
      #pragma unroll
      for (int n = 0; n < 2; ++n) {
        f32x4 s = zero4;
        s = MFMA16(af[m][0], bf[n][0], s);
        s = MFMA16(af[m][1], bf[n][1], s);
        #pragma unroll
        for (int r = 0; r < 4; ++r) lsum[m][r] += EXP2F(s[r]);
      }
    }
    __builtin_amdgcn_s_setprio(0);
    // no trailing barrier (3-deep rotation provides the ordering)
  }
#undef STAGE_KK

  #pragma unroll
  for (int m = 0; m < 4; ++m)
    #pragma unroll
    for (int r = 0; r < 4; ++r) {
      #pragma unroll
      for (int off = 1; off < 16; off <<= 1)
        lsum[m][r] += __shfl_xor(lsum[m][r], off);
    }
  if (lrow == 0) {
    #pragma unroll
    for (int m = 0; m < 4; ++m)
      #pragma unroll
      for (int r = 0; r < 4; ++r)
        red[wn][wm * 64 + m * 16 + sub * 4 + r] = lsum[m][r];
  }
  __syncthreads();
  if (tid < 128) {
    const float s = red[0][tid] + red[1][tid] + red[2][tid] + red[3][tid];
    Linv[((size_t)b * H_ + h) * Q_ + qb + tid] = 1.0f / (s * (float)H_);
  }
}

// ---------------------------------------------------------------------------
// Kernel 6 (pass B): attn weights (round-13 form)
// ---------------------------------------------------------------------------
__global__ __launch_bounds__(512) void k_attn_weights(
    const u16* __restrict__ qp, const u16* __restrict__ kp,
    const float* __restrict__ Linv, u16* __restrict__ attn)
{
  const int kv0 = blockIdx.x * 128, qb = blockIdx.y * 128, b = blockIdx.z;
  __shared__ u16 As[2][128 * 64];
  __shared__ u16 Bs[2][128 * 64];
  __shared__ float linv_s[H_][128];
  const int tid = threadIdx.x, lane = tid & 63, w = tid >> 6;
  const int wm = w >> 2, wn = w & 3;
  const int lrow = lane & 15, sub = lane >> 4, lrow7 = lrow & 7;

  {
    const int hh = tid >> 5, i0 = (tid & 31) * 4;
    *reinterpret_cast<float4*>(&linv_s[hh][i0]) =
        *reinterpret_cast<const float4*>(&Linv[((size_t)b * H_ + hh) * Q_ + qb + i0]);
  }
  __syncthreads();

#define STAGE_AB(buf, hh)                                                     \
  {                                                                           \
    _Pragma("unroll")                                                         \
    for (int i = 0; i < 2; ++i) {                                             \
      const int c = i * 512 + tid, r = c >> 3, u = (c & 7) ^ (r & 7);         \
      gl_lds16(&qp[((size_t)b * Q_ + qb + r) * D_ + (hh) * 64 + u * 8],       \
               &As[buf][c * 8]);                                              \
      gl_lds16(&kp[((size_t)b * KV_ + kv0 + r) * D_ + (hh) * 64 + u * 8],     \
               &Bs[buf][c * 8]);                                              \
    }                                                                         \
  }

  const f32x4 zero4 = {0.f, 0.f, 0.f, 0.f};
  f32x4 acc[4][2];
  #pragma unroll
  for (int m = 0; m < 4; ++m)
    #pragma unroll
    for (int n = 0; n < 2; ++n) acc[m][n] = zero4;

  STAGE_AB(0, 0);
  for (int h = 0; h < H_; ++h) {
    const int cur = h & 1;
    if (h + 1 < H_) {
      STAGE_AB(cur ^ 1, h + 1);
      wait_vmcnt<4>();
    } else {
      wait_vmcnt<0>();
    }
    barrier_raw();
    bf16x8 af[4][2], bf[2][2];
    #pragma unroll
    for (int m = 0; m < 4; ++m) {
      const int rA = wm * 64 + m * 16 + lrow;
      af[m][0] = *(const bf16x8*)&As[cur][rA * 64 + ((sub ^ lrow7) << 3)];
      af[m][1] = *(const bf16x8*)&As[cur][rA * 64 + (((4 + sub) ^ lrow7) << 3)];
    }
    #pragma unroll
    for (int n = 0; n < 2; ++n) {
      const int rB = wn * 32 + n * 16 + lrow;
      bf[n][0] = *(const bf16x8*)&Bs[cur][rB * 64 + ((sub ^ lrow7) << 3)];
      bf[n][1] = *(const bf16x8*)&Bs[cur][rB * 64 + (((4 + sub) ^ lrow7) << 3)];
    }
    f32x4 lv[4];
    #pragma unroll
    for (int m = 0; m < 4; ++m)
      lv[m] = *(const f32x4*)&linv_s[h][wm * 64 + m * 16 + sub * 4];
    __builtin_amdgcn_s_setprio(1);
    #pragma unroll
    for (int m = 0; m < 4; ++m) {
      #pragma unroll
      for (int n = 0; n < 2; ++n) {
        f32x4 s = zero4;
        s = MFMA16(af[m][0], bf[n][0], s);
        s = MFMA16(af[m][1], bf[n][1], s);
        #pragma unroll
        for (int r = 0; r < 4; ++r)
          acc[m][n][r] += EXP2F(s[r]) * lv[m][r];
      }
    }
    __builtin_amdgcn_s_setprio(0);
    barrier_raw();
  }
#undef STAGE_AB

  #pragma unroll
  for (int m = 0; m < 4; ++m) {
    #pragma unroll
    for (int n = 0; n < 2; ++n) {
      const int gcol = kv0 + wn * 32 + n * 16 + lrow;
      #pragma unroll
      for (int r = 0; r < 4; ++r) {
        const int grow = qb + wm * 64 + m * 16 + sub * 4 + r;
        attn[((size_t)b * Q_ + grow) * KV_ + gcol] = f2bf(acc[m][n][r]);
      }
    }
  }
}

// ---------------------------------------------------------------------------
// Launch
// ---------------------------------------------------------------------------
extern "C" void kernel_launch(void* const* d_in, const int* in_sizes, int n_in,
                              void* d_out, int out_size, void* d_ws, size_t ws_size,
                              hipStream_t stream)
{
  (void)in_sizes; (void)n_in; (void)out_size; (void)ws_size;
  const float* query = (const float*)d_in[0];
  const float* key   = (const float*)d_in[1];
  const float* value = (const float*)d_in[2];
  const float* wqn   = (const float*)d_in[3];
  const float* wkn   = (const float*)d_in[4];
  const float* Wq    = (const float*)d_in[5];
  const float* Wk    = (const float*)d_in[6];
  const float* bq    = (const float*)d_in[7];
  const float* bk    = (const float*)d_in[8];
  float* out = (float*)d_out;

  // workspace layout (~46.7 MB; attn aliases the dead qn+kn region)
  char* ws = (char*)d_ws;
  u16* qn   = (u16*)(ws);                 //  8 MiB  (B*Q, D)  bf16
  u16* attn = (u16*)(ws);                 // 16 MiB  (B, Q, KV) bf16 — alias qn+kn
  u16* qp   = (u16*)(ws + 16777216);      //  8 MiB  (B*Q, D)  bf16
  u16* kp   = (u16*)(ws + 25165824);      //  8 MiB  (B*KV, D) bf16
  u16* Wqb  = (u16*)(ws + 33554432);      //  4 MiB  (2, D, D) bf16 (Wq|Wk adjacent)
  u16* vT   = (u16*)(ws + 37748736);      //  8 MiB  (B, D, KV) bf16
  float* Linv = (float*)(ws + 46137344);  // 256 KiB (B, H, Q) fp32
  float* biasbuf = (float*)(ws + 46399488); // 8 KiB (2, D) fp32
  u16* kn = qn + 4194304;

  // merged prep: rmsnorm (2048) + Wcast (1024) + bias (1) + V transpose (1024)
  k_prep<<<dim3(4097), dim3(256), 0, stream>>>(
      query, key, wqn, wkn, Wq, Wk, bq, bk, value, qn, kn, Wqb, biasbuf, vT);

  // batched projections: z=0 -> qp = (qn@Wq^T + bq)*QSCALE ; z=1 -> kp = kn@Wk^T + bk
  k_gemm_bt<128, 128, 2, 4, true, true>
      <<<dim3(D_ / 128, (B_ * Q_) / 128, 2), dim3(512), 0, stream>>>(
      qn, D_, 4194304, Wqb, D_, 1048576, qp, D_, 4194304, D_, biasbuf);

  k_attn_rowsum<<<dim3(Q_ / 128, H_, B_), dim3(512), 0, stream>>>(qp, kp, Linv);
  k_attn_weights<<<dim3(KV_ / 128, Q_ / 128, B_), dim3(512), 0, stream>>>(qp, kp, Linv, attn);

  // PV: 3-deep single-barrier pipeline, 128x64 tiles -> 512 blocks (2/CU)
  k_gemm_pv3<<<dim3(D_ / 64, Q_ / 128, B_), dim3(512), 0, stream>>>(
      attn, (long)Q_ * KV_, vT, (long)D_ * KV_, out, (long)Q_ * D_);
}

// Round 18
// 125.348 us; speedup vs baseline: 1.0083x; 1.0083x over previous
//
#include <hip/hip_runtime.h>

#define B_  2
#define Q_  2048
#define KV_ 2048
#define D_  1024
#define H_  16
#define DH_ 64

// 0.125 * log2(e): folded into qp so attention scores feed exp2 directly
#define QSCALE 0.18033688011112042f

using u16 = unsigned short;
using bf16x8 = __attribute__((ext_vector_type(8))) short;
using f32x4  = __attribute__((ext_vector_type(4))) float;

__device__ __forceinline__ u16 f2bf(float x) {
  unsigned u = __float_as_uint(x);
  u += 0x7fffu + ((u >> 16) & 1u);   // round-to-nearest-even
  return (u16)(u >> 16);
}

__device__ __forceinline__ void gl_lds16(const void* g, void* l) {
  __builtin_amdgcn_global_load_lds(
      (const __attribute__((address_space(1))) void*)g,
      (__attribute__((address_space(3))) void*)l, 16, 0, 0);
}

// Counted vmcnt wait. static_assert: an uncovered N must be a COMPILE error
// (round-14 lesson: a silent fall-through = no wait = LDS race).
template<int N> __device__ __forceinline__ void wait_vmcnt() {
  static_assert(N == 0 || N == 1 || N == 2 || N == 3 || N == 4 ||
                N == 6 || N == 8, "wait_vmcnt: unsupported N");
  if constexpr (N == 0)      asm volatile("s_waitcnt vmcnt(0)" ::: "memory");
  else if constexpr (N == 1) asm volatile("s_waitcnt vmcnt(1)" ::: "memory");
  else if constexpr (N == 2) asm volatile("s_waitcnt vmcnt(2)" ::: "memory");
  else if constexpr (N == 3) asm volatile("s_waitcnt vmcnt(3)" ::: "memory");
  else if constexpr (N == 4) asm volatile("s_waitcnt vmcnt(4)" ::: "memory");
  else if constexpr (N == 6) asm volatile("s_waitcnt vmcnt(6)" ::: "memory");
  else if constexpr (N == 8) asm volatile("s_waitcnt vmcnt(8)" ::: "memory");
}
__device__ __forceinline__ void barrier_raw() {
  asm volatile("" ::: "memory");
  __builtin_amdgcn_s_barrier();
  asm volatile("" ::: "memory");
}

#define MFMA16(a, b, c) __builtin_amdgcn_mfma_f32_16x16x32_bf16((a), (b), (c), 0, 0, 0)
#define EXP2F(x) __builtin_amdgcn_exp2f(x)

// ---------------------------------------------------------------------------
// Kernel 1 (merged prep), grid 4097 (round-13 form)
// ---------------------------------------------------------------------------
__global__ __launch_bounds__(256) void k_prep(
    const float* __restrict__ q, const float* __restrict__ k,
    const float* __restrict__ wq, const float* __restrict__ wk,
    const float* __restrict__ Wq, const float* __restrict__ Wk,
    const float* __restrict__ bq, const float* __restrict__ bk,
    const float* __restrict__ v,
    u16* __restrict__ qn, u16* __restrict__ kn,
    u16* __restrict__ Wb, float* __restrict__ biasbuf,
    u16* __restrict__ vT)
{
  __shared__ char smem[64 * 72 * 2];
  const int bid = blockIdx.x, t = threadIdx.x;
  if (bid < 2048) {
    const int w = t >> 6, lane = t & 63;
    const int row = bid * 4 + w;
    const float* src; const float* wgt; u16* dst;
    if (row < B_ * Q_) {
      src = q + (size_t)row * D_; wgt = wq; dst = qn + (size_t)row * D_;
    } else {
      const int r2 = row - B_ * Q_;
      src = k + (size_t)r2 * D_; wgt = wk; dst = kn + (size_t)r2 * D_;
    }
    float4 v4[4];
    float ss = 0.f;
    #pragma unroll
    for (int i = 0; i < 4; ++i) {
      v4[i] = reinterpret_cast<const float4*>(src)[lane + 64 * i];
      ss += v4[i].x * v4[i].x + v4[i].y * v4[i].y
          + v4[i].z * v4[i].z + v4[i].w * v4[i].w;
    }
    #pragma unroll
    for (int off = 1; off < 64; off <<= 1) ss += __shfl_xor(ss, off);
    const float sc = rsqrtf(ss * (1.0f / D_) + 1.1920929e-07f);
    #pragma unroll
    for (int i = 0; i < 4; ++i) {
      const float4 wv = reinterpret_cast<const float4*>(wgt)[lane + 64 * i];
      ushort4 o;
      o.x = f2bf(v4[i].x * sc * wv.x);
      o.y = f2bf(v4[i].y * sc * wv.y);
      o.z = f2bf(v4[i].z * sc * wv.z);
      o.w = f2bf(v4[i].w * sc * wv.w);
      reinterpret_cast<ushort4*>(dst)[lane + 64 * i] = o;
    }
  } else if (bid < 3072) {
    const int pb = bid - 2048;
    #pragma unroll
    for (int rr = 0; rr < 2; ++rr) {
      const int i = pb * 512 + rr * 256 + t;
      const bool isK = i >= 262144;
      const int j = i & 262143;
      float4 vv = reinterpret_cast<const float4*>(isK ? Wk : Wq)[j];
      ushort4 o;
      o.x = f2bf(vv.x); o.y = f2bf(vv.y); o.z = f2bf(vv.z); o.w = f2bf(vv.w);
      reinterpret_cast<ushort4*>(Wb + (isK ? D_ * D_ : 0))[j] = o;
    }
  } else if (bid == 3072) {
    #pragma unroll
    for (int rr = 0; rr < 2; ++rr) {
      const int i = rr * 256 + t;
      float4 vv = (i < 256) ? reinterpret_cast<const float4*>(bq)[i]
                            : reinterpret_cast<const float4*>(bk)[i - 256];
      reinterpret_cast<float4*>(biasbuf)[i] = vv;
    }
  } else {
    const int tb = bid - 3073;
    const int kv0 = (tb & 31) * 64, d0 = ((tb >> 5) & 15) * 64, b = tb >> 9;
    u16 (*tile)[72] = (u16(*)[72])smem;
    #pragma unroll
    for (int i = 0; i < 16; ++i) {
      const int idx = i * 256 + t, r = idx >> 6, c = idx & 63;
      tile[r][c] = f2bf(v[((size_t)b * KV_ + kv0 + r) * D_ + d0 + c]);
    }
    __syncthreads();
    #pragma unroll
    for (int i = 0; i < 16; ++i) {
      const int idx = i * 256 + t, r = idx >> 6, c = idx & 63;
      vT[((size_t)b * D_ + d0 + r) * KV_ + kv0 + c] = tile[c][r];
    }
  }
}

// ---------------------------------------------------------------------------
// Kernel 4: C = A * B^T (+bias,*scale), bf16 in, fp32 accum. TM x TN tile,
// BK=64, 512 threads = 8 waves WM x WN, T2-swizzled LDS, 2-deep dbuf +
// counted-vmcnt pipeline. (round-13 form; used by the projections)
// ---------------------------------------------------------------------------
template<int TM, int TN, int WM, int WN, bool OUT_BF16, bool PROJ>
__global__ __launch_bounds__(512) void k_gemm_bt(
    const u16* __restrict__ A, int lda, long sA,
    const u16* __restrict__ Bm, int ldb, long sB,
    void* __restrict__ C, int ldc, long sC,
    int K, const float* __restrict__ bias)
{
  constexpr int RM = TM / WM / 16, RN = TN / WN / 16;
  constexpr int LA = TM / 64, LB = TN / 64;
  constexpr int NL = LA + LB;
  const int bb = blockIdx.z;
  const u16* Ab = A + (size_t)bb * sA;
  const u16* Bb = Bm + (size_t)bb * sB;
  const int row0 = blockIdx.y * TM, col0 = blockIdx.x * TN;
  __shared__ u16 As[2][TM * 64];
  __shared__ u16 Bs[2][TN * 64];
  const int tid = threadIdx.x, lane = tid & 63;
  const int w = tid >> 6, wm = w / WN, wn = w % WN;
  const int lrow = lane & 15, sub = lane >> 4, lrow7 = lrow & 7;
  const f32x4 zero4 = {0.f, 0.f, 0.f, 0.f};
  f32x4 acc[RM][RN];
  #pragma unroll
  for (int m = 0; m < RM; ++m)
    #pragma unroll
    for (int n = 0; n < RN; ++n) acc[m][n] = zero4;

  const int nk = K >> 6;

#define GEMM_STAGE(buf, kt)                                                   \
  {                                                                           \
    const int k0 = (kt) << 6;                                                 \
    _Pragma("unroll")                                                         \
    for (int i = 0; i < LA; ++i) {                                            \
      const int c = i * 512 + tid, r = c >> 3, u = (c & 7) ^ (r & 7);         \
      gl_lds16(Ab + (size_t)(row0 + r) * lda + k0 + u * 8, &As[buf][c * 8]);  \
    }                                                                         \
    _Pragma("unroll")                                                         \
    for (int i = 0; i < LB; ++i) {                                            \
      const int c = i * 512 + tid, r = c >> 3, u = (c & 7) ^ (r & 7);         \
      gl_lds16(Bb + (size_t)(col0 + r) * ldb + k0 + u * 8, &Bs[buf][c * 8]);  \
    }                                                                         \
  }

  GEMM_STAGE(0, 0);
  int cur = 0;
  for (int kt = 0; kt < nk; ++kt) {
    if (kt + 1 < nk) {
      GEMM_STAGE(cur ^ 1, kt + 1);
      wait_vmcnt<NL>();                  // previous stage done; next in flight
    } else {
      wait_vmcnt<0>();
    }
    barrier_raw();                       // buf[cur] visible to all waves
    #pragma unroll
    for (int ks = 0; ks < 2; ++ks) {
      bf16x8 af[RM], bfr[RN];
      #pragma unroll
      for (int m = 0; m < RM; ++m) {
        const int rA = wm * (TM / WM) + m * 16 + lrow;
        af[m] = *(const bf16x8*)&As[cur][rA * 64 + ((((ks << 2) + sub) ^ lrow7) << 3)];
      }
      #pragma unroll
      for (int n = 0; n < RN; ++n) {
        const int rB = wn * (TN / WN) + n * 16 + lrow;
        bfr[n] = *(const bf16x8*)&Bs[cur][rB * 64 + ((((ks << 2) + sub) ^ lrow7) << 3)];
      }
      #pragma unroll
      for (int m = 0; m < RM; ++m)
        #pragma unroll
        for (int n = 0; n < RN; ++n)
          acc[m][n] = MFMA16(af[m], bfr[n], acc[m][n]);
    }
    barrier_raw();                       // all waves done reading buf[cur]
    cur ^= 1;
  }
#undef GEMM_STAGE

  const int crow = sub * 4, ccol = lane & 15;
  const float scl = (PROJ && bb == 0) ? QSCALE : 1.0f;
  #pragma unroll
  for (int m = 0; m < RM; ++m) {
    #pragma unroll
    for (int n = 0; n < RN; ++n) {
      const int gcol = col0 + wn * (TN / WN) + n * 16 + ccol;
      const float badd = PROJ ? bias[bb * 1024 + gcol] : 0.0f;
      #pragma unroll
      for (int r = 0; r < 4; ++r) {
        const int grow = row0 + wm * (TM / WM) + m * 16 + crow + r;
        const float val = (acc[m][n][r] + badd) * scl;
        if (OUT_BF16)
          ((u16*)C)[(size_t)bb * sC + (size_t)grow * ldc + gcol] = f2bf(val);
        else
          ((float*)C)[(size_t)bb * sC + (size_t)grow * ldc + gcol] = val;
      }
    }
  }
}

// ---------------------------------------------------------------------------
// Kernel 4b: PV GEMM, 3-deep rotation, ONE barrier per K-step (round-16 form).
// ---------------------------------------------------------------------------
__global__ __launch_bounds__(512) void k_gemm_pv3(
    const u16* __restrict__ A, long sA,      // attn: Q x KV rows, lda=KV
    const u16* __restrict__ Bm, long sB,     // vT:   D x KV rows, ldb=KV
    float* __restrict__ C, long sC)          // out:  Q x D, fp32
{
  const int bb = blockIdx.z;
  const u16* Ab = A + (size_t)bb * sA;
  const u16* Bb = Bm + (size_t)bb * sB;
  const int row0 = blockIdx.y * 128, col0 = blockIdx.x * 64;
  __shared__ u16 As3[3][128 * 64];           // 48 KB
  __shared__ u16 Bs3[3][64 * 64];            // 24 KB
  const int tid = threadIdx.x, lane = tid & 63;
  const int w = tid >> 6, wm = w >> 1, wn = w & 1;   // 4M x 2N
  const int lrow = lane & 15, sub = lane >> 4, lrow7 = lrow & 7;
  const f32x4 zero4 = {0.f, 0.f, 0.f, 0.f};
  f32x4 acc[2][2];
  #pragma unroll
  for (int m = 0; m < 2; ++m)
    #pragma unroll
    for (int n = 0; n < 2; ++n) acc[m][n] = zero4;

  const int nk = KV_ >> 6;                   // 32 K-tiles

#define PV_STAGE(buf, kt)                                                     \
  {                                                                           \
    const int k0 = (kt) << 6;                                                 \
    _Pragma("unroll")                                                         \
    for (int i = 0; i < 2; ++i) {                                             \
      const int c = i * 512 + tid, r = c >> 3, u = (c & 7) ^ (r & 7);         \
      gl_lds16(Ab + (size_t)(row0 + r) * KV_ + k0 + u * 8, &As3[buf][c * 8]); \
    }                                                                         \
    {                                                                         \
      const int c = tid, r = c >> 3, u = (c & 7) ^ (r & 7);                   \
      gl_lds16(Bb + (size_t)(col0 + r) * KV_ + k0 + u * 8, &Bs3[buf][c * 8]); \
    }                                                                         \
  }

  PV_STAGE(0, 0);
  PV_STAGE(1, 1);
  for (int kt = 0; kt < nk; ++kt) {
    const int cb = kt % 3;
    if (kt + 1 < nk) wait_vmcnt<3>();        // tile kt landed; kt+1 in flight
    else             wait_vmcnt<0>();
    barrier_raw();                           // orders vs compute(kt-1) too
    if (kt + 2 < nk) PV_STAGE((kt + 2) % 3, kt + 2);
    #pragma unroll
    for (int ks = 0; ks < 2; ++ks) {
      bf16x8 af[2], bfr[2];
      #pragma unroll
      for (int m = 0; m < 2; ++m) {
        const int rA = wm * 32 + m * 16 + lrow;
        af[m] = *(const bf16x8*)&As3[cb][rA * 64 + ((((ks << 2) + sub) ^ lrow7) << 3)];
      }
      #pragma unroll
      for (int n = 0; n < 2; ++n) {
        const int rB = wn * 32 + n * 16 + lrow;
        bfr[n] = *(const bf16x8*)&Bs3[cb][rB * 64 + ((((ks << 2) + sub) ^ lrow7) << 3)];
      }
      #pragma unroll
      for (int m = 0; m < 2; ++m)
        #pragma unroll
        for (int n = 0; n < 2; ++n)
          acc[m][n] = MFMA16(af[m], bfr[n], acc[m][n]);
    }
  }
#undef PV_STAGE

  const int crow = sub * 4, ccol = lane & 15;
  #pragma unroll
  for (int m = 0; m < 2; ++m) {
    #pragma unroll
    for (int n = 0; n < 2; ++n) {
      const int gcol = col0 + wn * 32 + n * 16 + ccol;
      #pragma unroll
      for (int r = 0; r < 4; ++r) {
        const int grow = row0 + wm * 32 + m * 16 + crow + r;
        C[(size_t)bb * sC + (size_t)grow * D_ + gcol] = acc[m][n][r];
      }
    }
  }
}

// ---------------------------------------------------------------------------
// Kernel 5 (pass A): Linv[b,h,i] = 1 / (H * sum_j 2^s(i,j))   (qp pre-scaled)
// block = (128 q-rows, head, batch), 8 waves 2x4 (64q x 32kv). Aq staged
// once; K 128-tiles 2-deep dbuf + counted vmcnt (round-16 best form).
// ---------------------------------------------------------------------------
__global__ __launch_bounds__(512) void k_attn_rowsum(
    const u16* __restrict__ qp, const u16* __restrict__ kp,
    float* __restrict__ Linv)
{
  const int qb = blockIdx.x * 128, h = blockIdx.y, b = blockIdx.z;
  __shared__ u16 Aq[128 * 64];
  __shared__ u16 Kk[2][128 * 64];
  __shared__ float red[4][128];
  const int tid = threadIdx.x, lane = tid & 63, w = tid >> 6;
  const int wm = w >> 2, wn = w & 3;
  const int lrow = lane & 15, sub = lane >> 4, lrow7 = lrow & 7;

  #pragma unroll
  for (int i = 0; i < 2; ++i) {
    const int c = i * 512 + tid, r = c >> 3, u = (c & 7) ^ (r & 7);
    gl_lds16(&qp[((size_t)b * Q_ + qb + r) * D_ + h * 64 + u * 8], &Aq[c * 8]);
  }

#define STAGE_KK(buf, kvt)                                                    \
  {                                                                           \
    _Pragma("unroll")                                                         \
    for (int i = 0; i < 2; ++i) {                                             \
      const int c = i * 512 + tid, r = c >> 3, u = (c & 7) ^ (r & 7);         \
      gl_lds16(&kp[((size_t)b * KV_ + (kvt) * 128 + r) * D_ + h * 64 + u * 8],\
               &Kk[buf][c * 8]);                                              \
    }                                                                         \
  }

  STAGE_KK(0, 0);
  const f32x4 zero4 = {0.f, 0.f, 0.f, 0.f};
  float lsum[4][4];
  #pragma unroll
  for (int m = 0; m < 4; ++m)
    #pragma unroll
    for (int r = 0; r < 4; ++r) lsum[m][r] = 0.f;
  bf16x8 af[4][2];

  for (int kvt = 0; kvt < KV_ / 128; ++kvt) {
    const int cur = kvt & 1;
    if (kvt + 1 < KV_ / 128) {
      STAGE_KK(cur ^ 1, kvt + 1);
      wait_vmcnt<2>();
    } else {
      wait_vmcnt<0>();
    }
    barrier_raw();
    if (kvt == 0) {
      #pragma unroll
      for (int m = 0; m < 4; ++m) {
        const int rA = wm * 64 + m * 16 + lrow;
        af[m][0] = *(const bf16x8*)&Aq[rA * 64 + ((sub ^ lrow7) << 3)];
        af[m][1] = *(const bf16x8*)&Aq[rA * 64 + (((4 + sub) ^ lrow7) << 3)];
      }
    }
    bf16x8 bf[2][2];
    #pragma unroll
    for (int n = 0; n < 2; ++n) {
      const int rB = wn * 32 + n * 16 + lrow;
      bf[n][0] = *(const bf16x8*)&Kk[cur][rB * 64 + ((sub ^ lrow7) << 3)];
      bf[n][1] = *(const bf16x8*)&Kk[cur][rB * 64 + (((4 + sub) ^ lrow7) << 3)];
    }
    __builtin_amdgcn_s_setprio(1);
    #pragma unroll
    for (int m = 0; m < 4; ++m) {
      #pragma unroll
      for (int n = 0; n < 2; ++n) {
        f32x4 s = zero4;
        s = MFMA16(af[m][0], bf[n][0], s);
        s = MFMA16(af[m][1], bf[n][1], s);
        #pragma unroll
        for (int r = 0; r < 4; ++r) lsum[m][r] += EXP2F(s[r]);
      }
    }
    __builtin_amdgcn_s_setprio(0);
    barrier_raw();
  }
#undef STAGE_KK

  #pragma unroll
  for (int m = 0; m < 4; ++m)
    #pragma unroll
    for (int r = 0; r < 4; ++r) {
      #pragma unroll
      for (int off = 1; off < 16; off <<= 1)
        lsum[m][r] += __shfl_xor(lsum[m][r], off);
    }
  if (lrow == 0) {
    #pragma unroll
    for (int m = 0; m < 4; ++m)
      #pragma unroll
      for (int r = 0; r < 4; ++r)
        red[wn][wm * 64 + m * 16 + sub * 4 + r] = lsum[m][r];
  }
  __syncthreads();
  if (tid < 128) {
    const float s = red[0][tid] + red[1][tid] + red[2][tid] + red[3][tid];
    Linv[((size_t)b * H_ + h) * Q_ + qb + tid] = 1.0f / (s * (float)H_);
  }
}

// ---------------------------------------------------------------------------
// Kernel 6 (pass B): attn weights (round-13 form)
// ---------------------------------------------------------------------------
__global__ __launch_bounds__(512) void k_attn_weights(
    const u16* __restrict__ qp, const u16* __restrict__ kp,
    const float* __restrict__ Linv, u16* __restrict__ attn)
{
  const int kv0 = blockIdx.x * 128, qb = blockIdx.y * 128, b = blockIdx.z;
  __shared__ u16 As[2][128 * 64];
  __shared__ u16 Bs[2][128 * 64];
  __shared__ float linv_s[H_][128];
  const int tid = threadIdx.x, lane = tid & 63, w = tid >> 6;
  const int wm = w >> 2, wn = w & 3;
  const int lrow = lane & 15, sub = lane >> 4, lrow7 = lrow & 7;

  {
    const int hh = tid >> 5, i0 = (tid & 31) * 4;
    *reinterpret_cast<float4*>(&linv_s[hh][i0]) =
        *reinterpret_cast<const float4*>(&Linv[((size_t)b * H_ + hh) * Q_ + qb + i0]);
  }
  __syncthreads();

#define STAGE_AB(buf, hh)                                                     \
  {                                                                           \
    _Pragma("unroll")                                                         \
    for (int i = 0; i < 2; ++i) {                                             \
      const int c = i * 512 + tid, r = c >> 3, u = (c & 7) ^ (r & 7);         \
      gl_lds16(&qp[((size_t)b * Q_ + qb + r) * D_ + (hh) * 64 + u * 8],       \
               &As[buf][c * 8]);                                              \
      gl_lds16(&kp[((size_t)b * KV_ + kv0 + r) * D_ + (hh) * 64 + u * 8],     \
               &Bs[buf][c * 8]);                                              \
    }                                                                         \
  }

  const f32x4 zero4 = {0.f, 0.f, 0.f, 0.f};
  f32x4 acc[4][2];
  #pragma unroll
  for (int m = 0; m < 4; ++m)
    #pragma unroll
    for (int n = 0; n < 2; ++n) acc[m][n] = zero4;

  STAGE_AB(0, 0);
  for (int h = 0; h < H_; ++h) {
    const int cur = h & 1;
    if (h + 1 < H_) {
      STAGE_AB(cur ^ 1, h + 1);
      wait_vmcnt<4>();
    } else {
      wait_vmcnt<0>();
    }
    barrier_raw();
    bf16x8 af[4][2], bf[2][2];
    #pragma unroll
    for (int m = 0; m < 4; ++m) {
      const int rA = wm * 64 + m * 16 + lrow;
      af[m][0] = *(const bf16x8*)&As[cur][rA * 64 + ((sub ^ lrow7) << 3)];
      af[m][1] = *(const bf16x8*)&As[cur][rA * 64 + (((4 + sub) ^ lrow7) << 3)];
    }
    #pragma unroll
    for (int n = 0; n < 2; ++n) {
      const int rB = wn * 32 + n * 16 + lrow;
      bf[n][0] = *(const bf16x8*)&Bs[cur][rB * 64 + ((sub ^ lrow7) << 3)];
      bf[n][1] = *(const bf16x8*)&Bs[cur][rB * 64 + (((4 + sub) ^ lrow7) << 3)];
    }
    f32x4 lv[4];
    #pragma unroll
    for (int m = 0; m < 4; ++m)
      lv[m] = *(const f32x4*)&linv_s[h][wm * 64 + m * 16 + sub * 4];
    __builtin_amdgcn_s_setprio(1);
    #pragma unroll
    for (int m = 0; m < 4; ++m) {
      #pragma unroll
      for (int n = 0; n < 2; ++n) {
        f32x4 s = zero4;
        s = MFMA16(af[m][0], bf[n][0], s);
        s = MFMA16(af[m][1], bf[n][1], s);
        #pragma unroll
        for (int r = 0; r < 4; ++r)
          acc[m][n][r] += EXP2F(s[r]) * lv[m][r];
      }
    }
    __builtin_amdgcn_s_setprio(0);
    barrier_raw();
  }
#undef STAGE_AB

  #pragma unroll
  for (int m = 0; m < 4; ++m) {
    #pragma unroll
    for (int n = 0; n < 2; ++n) {
      const int gcol = kv0 + wn * 32 + n * 16 + lrow;
      #pragma unroll
      for (int r = 0; r < 4; ++r) {
        const int grow = qb + wm * 64 + m * 16 + sub * 4 + r;
        attn[((size_t)b * Q_ + grow) * KV_ + gcol] = f2bf(acc[m][n][r]);
      }
    }
  }
}

// ---------------------------------------------------------------------------
// Launch
// ---------------------------------------------------------------------------
extern "C" void kernel_launch(void* const* d_in, const int* in_sizes, int n_in,
                              void* d_out, int out_size, void* d_ws, size_t ws_size,
                              hipStream_t stream)
{
  (void)in_sizes; (void)n_in; (void)out_size; (void)ws_size;
  const float* query = (const float*)d_in[0];
  const float* key   = (const float*)d_in[1];
  const float* value = (const float*)d_in[2];
  const float* wqn   = (const float*)d_in[3];
  const float* wkn   = (const float*)d_in[4];
  const float* Wq    = (const float*)d_in[5];
  const float* Wk    = (const float*)d_in[6];
  const float* bq    = (const float*)d_in[7];
  const float* bk    = (const float*)d_in[8];
  float* out = (float*)d_out;

  // workspace layout (~46.7 MB; attn aliases the dead qn+kn region)
  char* ws = (char*)d_ws;
  u16* qn   = (u16*)(ws);                 //  8 MiB  (B*Q, D)  bf16
  u16* attn = (u16*)(ws);                 // 16 MiB  (B, Q, KV) bf16 — alias qn+kn
  u16* qp   = (u16*)(ws + 16777216);      //  8 MiB  (B*Q, D)  bf16
  u16* kp   = (u16*)(ws + 25165824);      //  8 MiB  (B*KV, D) bf16
  u16* Wqb  = (u16*)(ws + 33554432);      //  4 MiB  (2, D, D) bf16 (Wq|Wk adjacent)
  u16* vT   = (u16*)(ws + 37748736);      //  8 MiB  (B, D, KV) bf16
  float* Linv = (float*)(ws + 46137344);  // 256 KiB (B, H, Q) fp32
  float* biasbuf = (float*)(ws + 46399488); // 8 KiB (2, D) fp32
  u16* kn = qn + 4194304;

  // merged prep: rmsnorm (2048) + Wcast (1024) + bias (1) + V transpose (1024)
  k_prep<<<dim3(4097), dim3(256), 0, stream>>>(
      query, key, wqn, wkn, Wq, Wk, bq, bk, value, qn, kn, Wqb, biasbuf, vT);

  // batched projections: z=0 -> qp = (qn@Wq^T + bq)*QSCALE ; z=1 -> kp = kn@Wk^T + bk
  k_gemm_bt<128, 128, 2, 4, true, true>
      <<<dim3(D_ / 128, (B_ * Q_) / 128, 2), dim3(512), 0, stream>>>(
      qn, D_, 4194304, Wqb, D_, 1048576, qp, D_, 4194304, D_, biasbuf);

  k_attn_rowsum<<<dim3(Q_ / 128, H_, B_), dim3(512), 0, stream>>>(qp, kp, Linv);
  k_attn_weights<<<dim3(KV_ / 128, Q_ / 128, B_), dim3(512), 0, stream>>>(qp, kp, Linv, attn);

  // PV: 3-deep single-barrier pipeline, 128x64 tiles -> 512 blocks (2/CU)
  k_gemm_pv3<<<dim3(D_ / 64, Q_ / 128, B_), dim3(512), 0, stream>>>(
      attn, (long)Q_ * KV_, vT, (long)D_ * KV_, out, (long)Q_ * D_);
}

// Round 19
// 120.892 us; speedup vs baseline: 1.0454x; 1.0369x over previous
//
#include <hip/hip_runtime.h>

#define B_  2
#define Q_  2048
#define KV_ 2048
#define D_  1024
#define H_  16
#define DH_ 64

// 0.125 * log2(e): folded into qp so attention scores feed exp2 directly
#define QSCALE 0.18033688011112042f

using u16 = unsigned short;
using bf16x8 = __attribute__((ext_vector_type(8))) short;
using f32x4  = __attribute__((ext_vector_type(4))) float;

__device__ __forceinline__ u16 f2bf(float x) {
  unsigned u = __float_as_uint(x);
  u += 0x7fffu + ((u >> 16) & 1u);   // round-to-nearest-even
  return (u16)(u >> 16);
}

__device__ __forceinline__ void gl_lds16(const void* g, void* l) {
  __builtin_amdgcn_global_load_lds(
      (const __attribute__((address_space(1))) void*)g,
      (__attribute__((address_space(3))) void*)l, 16, 0, 0);
}

// Counted vmcnt wait. static_assert: an uncovered N must be a COMPILE error
// (round-14 lesson: a silent fall-through = no wait = LDS race).
template<int N> __device__ __forceinline__ void wait_vmcnt() {
  static_assert(N == 0 || N == 1 || N == 2 || N == 3 || N == 4 ||
                N == 6 || N == 8, "wait_vmcnt: unsupported N");
  if constexpr (N == 0)      asm volatile("s_waitcnt vmcnt(0)" ::: "memory");
  else if constexpr (N == 1) asm volatile("s_waitcnt vmcnt(1)" ::: "memory");
  else if constexpr (N == 2) asm volatile("s_waitcnt vmcnt(2)" ::: "memory");
  else if constexpr (N == 3) asm volatile("s_waitcnt vmcnt(3)" ::: "memory");
  else if constexpr (N == 4) asm volatile("s_waitcnt vmcnt(4)" ::: "memory");
  else if constexpr (N == 6) asm volatile("s_waitcnt vmcnt(6)" ::: "memory");
  else if constexpr (N == 8) asm volatile("s_waitcnt vmcnt(8)" ::: "memory");
}
__device__ __forceinline__ void barrier_raw() {
  asm volatile("" ::: "memory");
  __builtin_amdgcn_s_barrier();
  asm volatile("" ::: "memory");
}

// T1 XCD-aware bijective block swizzle. Valid for grids whose per-z slice is
// exactly 256 blocks (256 % 8 XCDs == 0, and z-slice offsets stay phase-
// aligned). Consecutive WORK ids land on one XCD chunk -> blocks sharing an
// operand panel hit the same per-XCD L2 instead of 8 of them.
__device__ __forceinline__ void xcd_swz(int& bx, int& by) {
  const int gx = (int)gridDim.x;
  const int lin = by * gx + bx;                  // 0..255 within z-slice
  const int nl = (lin & 7) * 32 + (lin >> 3);    // bijective chunk remap
  bx = nl % gx;
  by = nl / gx;
}

#define MFMA16(a, b, c) __builtin_amdgcn_mfma_f32_16x16x32_bf16((a), (b), (c), 0, 0, 0)
#define EXP2F(x) __builtin_amdgcn_exp2f(x)

// ---------------------------------------------------------------------------
// Kernel 1 (merged prep), grid 4097 (round-13 form)
// ---------------------------------------------------------------------------
__global__ __launch_bounds__(256) void k_prep(
    const float* __restrict__ q, const float* __restrict__ k,
    const float* __restrict__ wq, const float* __restrict__ wk,
    const float* __restrict__ Wq, const float* __restrict__ Wk,
    const float* __restrict__ bq, const float* __restrict__ bk,
    const float* __restrict__ v,
    u16* __restrict__ qn, u16* __restrict__ kn,
    u16* __restrict__ Wb, float* __restrict__ biasbuf,
    u16* __restrict__ vT)
{
  __shared__ char smem[64 * 72 * 2];
  const int bid = blockIdx.x, t = threadIdx.x;
  if (bid < 2048) {
    const int w = t >> 6, lane = t & 63;
    const int row = bid * 4 + w;
    const float* src; const float* wgt; u16* dst;
    if (row < B_ * Q_) {
      src = q + (size_t)row * D_; wgt = wq; dst = qn + (size_t)row * D_;
    } else {
      const int r2 = row - B_ * Q_;
      src = k + (size_t)r2 * D_; wgt = wk; dst = kn + (size_t)r2 * D_;
    }
    float4 v4[4];
    float ss = 0.f;
    #pragma unroll
    for (int i = 0; i < 4; ++i) {
      v4[i] = reinterpret_cast<const float4*>(src)[lane + 64 * i];
      ss += v4[i].x * v4[i].x + v4[i].y * v4[i].y
          + v4[i].z * v4[i].z + v4[i].w * v4[i].w;
    }
    #pragma unroll
    for (int off = 1; off < 64; off <<= 1) ss += __shfl_xor(ss, off);
    const float sc = rsqrtf(ss * (1.0f / D_) + 1.1920929e-07f);
    #pragma unroll
    for (int i = 0; i < 4; ++i) {
      const float4 wv = reinterpret_cast<const float4*>(wgt)[lane + 64 * i];
      ushort4 o;
      o.x = f2bf(v4[i].x * sc * wv.x);
      o.y = f2bf(v4[i].y * sc * wv.y);
      o.z = f2bf(v4[i].z * sc * wv.z);
      o.w = f2bf(v4[i].w * sc * wv.w);
      reinterpret_cast<ushort4*>(dst)[lane + 64 * i] = o;
    }
  } else if (bid < 3072) {
    const int pb = bid - 2048;
    #pragma unroll
    for (int rr = 0; rr < 2; ++rr) {
      const int i = pb * 512 + rr * 256 + t;
      const bool isK = i >= 262144;
      const int j = i & 262143;
      float4 vv = reinterpret_cast<const float4*>(isK ? Wk : Wq)[j];
      ushort4 o;
      o.x = f2bf(vv.x); o.y = f2bf(vv.y); o.z = f2bf(vv.z); o.w = f2bf(vv.w);
      reinterpret_cast<ushort4*>(Wb + (isK ? D_ * D_ : 0))[j] = o;
    }
  } else if (bid == 3072) {
    #pragma unroll
    for (int rr = 0; rr < 2; ++rr) {
      const int i = rr * 256 + t;
      float4 vv = (i < 256) ? reinterpret_cast<const float4*>(bq)[i]
                            : reinterpret_cast<const float4*>(bk)[i - 256];
      reinterpret_cast<float4*>(biasbuf)[i] = vv;
    }
  } else {
    const int tb = bid - 3073;
    const int kv0 = (tb & 31) * 64, d0 = ((tb >> 5) & 15) * 64, b = tb >> 9;
    u16 (*tile)[72] = (u16(*)[72])smem;
    #pragma unroll
    for (int i = 0; i < 16; ++i) {
      const int idx = i * 256 + t, r = idx >> 6, c = idx & 63;
      tile[r][c] = f2bf(v[((size_t)b * KV_ + kv0 + r) * D_ + d0 + c]);
    }
    __syncthreads();
    #pragma unroll
    for (int i = 0; i < 16; ++i) {
      const int idx = i * 256 + t, r = idx >> 6, c = idx & 63;
      vT[((size_t)b * D_ + d0 + r) * KV_ + kv0 + c] = tile[c][r];
    }
  }
}

// ---------------------------------------------------------------------------
// Kernel 4: C = A * B^T (+bias,*scale), bf16 in, fp32 accum. TM x TN tile,
// BK=64, 512 threads = 8 waves WM x WN, T2-swizzled LDS, 2-deep dbuf +
// counted-vmcnt pipeline + T1 XCD block swizzle. (used by the projections)
// ---------------------------------------------------------------------------
template<int TM, int TN, int WM, int WN, bool OUT_BF16, bool PROJ>
__global__ __launch_bounds__(512) void k_gemm_bt(
    const u16* __restrict__ A, int lda, long sA,
    const u16* __restrict__ Bm, int ldb, long sB,
    void* __restrict__ C, int ldc, long sC,
    int K, const float* __restrict__ bias)
{
  constexpr int RM = TM / WM / 16, RN = TN / WN / 16;
  constexpr int LA = TM / 64, LB = TN / 64;
  constexpr int NL = LA + LB;
  const int bb = blockIdx.z;
  const u16* Ab = A + (size_t)bb * sA;
  const u16* Bb = Bm + (size_t)bb * sB;
  int bx = blockIdx.x, by = blockIdx.y;
  xcd_swz(bx, by);
  const int row0 = by * TM, col0 = bx * TN;
  __shared__ u16 As[2][TM * 64];
  __shared__ u16 Bs[2][TN * 64];
  const int tid = threadIdx.x, lane = tid & 63;
  const int w = tid >> 6, wm = w / WN, wn = w % WN;
  const int lrow = lane & 15, sub = lane >> 4, lrow7 = lrow & 7;
  const f32x4 zero4 = {0.f, 0.f, 0.f, 0.f};
  f32x4 acc[RM][RN];
  #pragma unroll
  for (int m = 0; m < RM; ++m)
    #pragma unroll
    for (int n = 0; n < RN; ++n) acc[m][n] = zero4;

  const int nk = K >> 6;

#define GEMM_STAGE(buf, kt)                                                   \
  {                                                                           \
    const int k0 = (kt) << 6;                                                 \
    _Pragma("unroll")                                                         \
    for (int i = 0; i < LA; ++i) {                                            \
      const int c = i * 512 + tid, r = c >> 3, u = (c & 7) ^ (r & 7);         \
      gl_lds16(Ab + (size_t)(row0 + r) * lda + k0 + u * 8, &As[buf][c * 8]);  \
    }                                                                         \
    _Pragma("unroll")                                                         \
    for (int i = 0; i < LB; ++i) {                                            \
      const int c = i * 512 + tid, r = c >> 3, u = (c & 7) ^ (r & 7);         \
      gl_lds16(Bb + (size_t)(col0 + r) * ldb + k0 + u * 8, &Bs[buf][c * 8]);  \
    }                                                                         \
  }

  GEMM_STAGE(0, 0);
  int cur = 0;
  for (int kt = 0; kt < nk; ++kt) {
    if (kt + 1 < nk) {
      GEMM_STAGE(cur ^ 1, kt + 1);
      wait_vmcnt<NL>();                  // previous stage done; next in flight
    } else {
      wait_vmcnt<0>();
    }
    barrier_raw();                       // buf[cur] visible to all waves
    #pragma unroll
    for (int ks = 0; ks < 2; ++ks) {
      bf16x8 af[RM], bfr[RN];
      #pragma unroll
      for (int m = 0; m < RM; ++m) {
        const int rA = wm * (TM / WM) + m * 16 + lrow;
        af[m] = *(const bf16x8*)&As[cur][rA * 64 + ((((ks << 2) + sub) ^ lrow7) << 3)];
      }
      #pragma unroll
      for (int n = 0; n < RN; ++n) {
        const int rB = wn * (TN / WN) + n * 16 + lrow;
        bfr[n] = *(const bf16x8*)&Bs[cur][rB * 64 + ((((ks << 2) + sub) ^ lrow7) << 3)];
      }
      #pragma unroll
      for (int m = 0; m < RM; ++m)
        #pragma unroll
        for (int n = 0; n < RN; ++n)
          acc[m][n] = MFMA16(af[m], bfr[n], acc[m][n]);
    }
    barrier_raw();                       // all waves done reading buf[cur]
    cur ^= 1;
  }
#undef GEMM_STAGE

  const int crow = sub * 4, ccol = lane & 15;
  const float scl = (PROJ && bb == 0) ? QSCALE : 1.0f;
  #pragma unroll
  for (int m = 0; m < RM; ++m) {
    #pragma unroll
    for (int n = 0; n < RN; ++n) {
      const int gcol = col0 + wn * (TN / WN) + n * 16 + ccol;
      const float badd = PROJ ? bias[bb * 1024 + gcol] : 0.0f;
      #pragma unroll
      for (int r = 0; r < 4; ++r) {
        const int grow = row0 + wm * (TM / WM) + m * 16 + crow + r;
        const float val = (acc[m][n][r] + badd) * scl;
        if (OUT_BF16)
          ((u16*)C)[(size_t)bb * sC + (size_t)grow * ldc + gcol] = f2bf(val);
        else
          ((float*)C)[(size_t)bb * sC + (size_t)grow * ldc + gcol] = val;
      }
    }
  }
}

// ---------------------------------------------------------------------------
// Kernel 4b: PV GEMM, 3-deep rotation, ONE barrier per K-step + XCD swizzle.
// ---------------------------------------------------------------------------
__global__ __launch_bounds__(512) void k_gemm_pv3(
    const u16* __restrict__ A, long sA,      // attn: Q x KV rows, lda=KV
    const u16* __restrict__ Bm, long sB,     // vT:   D x KV rows, ldb=KV
    float* __restrict__ C, long sC)          // out:  Q x D, fp32
{
  const int bb = blockIdx.z;
  const u16* Ab = A + (size_t)bb * sA;
  const u16* Bb = Bm + (size_t)bb * sB;
  int bx = blockIdx.x, by = blockIdx.y;
  xcd_swz(bx, by);
  const int row0 = by * 128, col0 = bx * 64;
  __shared__ u16 As3[3][128 * 64];           // 48 KB
  __shared__ u16 Bs3[3][64 * 64];            // 24 KB
  const int tid = threadIdx.x, lane = tid & 63;
  const int w = tid >> 6, wm = w >> 1, wn = w & 1;   // 4M x 2N
  const int lrow = lane & 15, sub = lane >> 4, lrow7 = lrow & 7;
  const f32x4 zero4 = {0.f, 0.f, 0.f, 0.f};
  f32x4 acc[2][2];
  #pragma unroll
  for (int m = 0; m < 2; ++m)
    #pragma unroll
    for (int n = 0; n < 2; ++n) acc[m][n] = zero4;

  const int nk = KV_ >> 6;                   // 32 K-tiles

#define PV_STAGE(buf, kt)                                                     \
  {                                                                           \
    const int k0 = (kt) << 6;                                                 \
    _Pragma("unroll")                                                         \
    for (int i = 0; i < 2; ++i) {                                             \
      const int c = i * 512 + tid, r = c >> 3, u = (c & 7) ^ (r & 7);         \
      gl_lds16(Ab + (size_t)(row0 + r) * KV_ + k0 + u * 8, &As3[buf][c * 8]); \
    }                                                                         \
    {                                                                         \
      const int c = tid, r = c >> 3, u = (c & 7) ^ (r & 7);                   \
      gl_lds16(Bb + (size_t)(col0 + r) * KV_ + k0 + u * 8, &Bs3[buf][c * 8]); \
    }                                                                         \
  }

  PV_STAGE(0, 0);
  PV_STAGE(1, 1);
  for (int kt = 0; kt < nk; ++kt) {
    const int cb = kt % 3;
    if (kt + 1 < nk) wait_vmcnt<3>();        // tile kt landed; kt+1 in flight
    else             wait_vmcnt<0>();
    barrier_raw();                           // orders vs compute(kt-1) too
    if (kt + 2 < nk) PV_STAGE((kt + 2) % 3, kt + 2);
    #pragma unroll
    for (int ks = 0; ks < 2; ++ks) {
      bf16x8 af[2], bfr[2];
      #pragma unroll
      for (int m = 0; m < 2; ++m) {
        const int rA = wm * 32 + m * 16 + lrow;
        af[m] = *(const bf16x8*)&As3[cb][rA * 64 + ((((ks << 2) + sub) ^ lrow7) << 3)];
      }
      #pragma unroll
      for (int n = 0; n < 2; ++n) {
        const int rB = wn * 32 + n * 16 + lrow;
        bfr[n] = *(const bf16x8*)&Bs3[cb][rB * 64 + ((((ks << 2) + sub) ^ lrow7) << 3)];
      }
      #pragma unroll
      for (int m = 0; m < 2; ++m)
        #pragma unroll
        for (int n = 0; n < 2; ++n)
          acc[m][n] = MFMA16(af[m], bfr[n], acc[m][n]);
    }
  }
#undef PV_STAGE

  const int crow = sub * 4, ccol = lane & 15;
  #pragma unroll
  for (int m = 0; m < 2; ++m) {
    #pragma unroll
    for (int n = 0; n < 2; ++n) {
      const int gcol = col0 + wn * 32 + n * 16 + ccol;
      #pragma unroll
      for (int r = 0; r < 4; ++r) {
        const int grow = row0 + wm * 32 + m * 16 + crow + r;
        C[(size_t)bb * sC + (size_t)grow * D_ + gcol] = acc[m][n][r];
      }
    }
  }
}

// ---------------------------------------------------------------------------
// Kernel 5 (pass A): Linv[b,h,i] = 1 / (H * sum_j 2^s(i,j))   (qp pre-scaled)
// block = (128 q-rows, head, batch), 8 waves 2x4 (64q x 32kv). Aq staged
// once; K 128-tiles 2-deep dbuf + counted vmcnt + XCD swizzle (blocks of a
// head chunk to one XCD -> its 256 KB kp slice stays in one L2).
// ---------------------------------------------------------------------------
__global__ __launch_bounds__(512) void k_attn_rowsum(
    const u16* __restrict__ qp, const u16* __restrict__ kp,
    float* __restrict__ Linv)
{
  int bx = blockIdx.x, by = blockIdx.y;
  xcd_swz(bx, by);
  const int qb = bx * 128, h = by, b = blockIdx.z;
  __shared__ u16 Aq[128 * 64];
  __shared__ u16 Kk[2][128 * 64];
  __shared__ float red[4][128];
  const int tid = threadIdx.x, lane = tid & 63, w = tid >> 6;
  const int wm = w >> 2, wn = w & 3;
  const int lrow = lane & 15, sub = lane >> 4, lrow7 = lrow & 7;

  #pragma unroll
  for (int i = 0; i < 2; ++i) {
    const int c = i * 512 + tid, r = c >> 3, u = (c & 7) ^ (r & 7);
    gl_lds16(&qp[((size_t)b * Q_ + qb + r) * D_ + h * 64 + u * 8], &Aq[c * 8]);
  }

#define STAGE_KK(buf, kvt)                                                    \
  {                                                                           \
    _Pragma("unroll")                                                         \
    for (int i = 0; i < 2; ++i) {                                             \
      const int c = i * 512 + tid, r = c >> 3, u = (c & 7) ^ (r & 7);         \
      gl_lds16(&kp[((size_t)b * KV_ + (kvt) * 128 + r) * D_ + h * 64 + u * 8],\
               &Kk[buf][c * 8]);                                              \
    }                                                                         \
  }

  STAGE_KK(0, 0);
  const f32x4 zero4 = {0.f, 0.f, 0.f, 0.f};
  float lsum[4][4];
  #pragma unroll
  for (int m = 0; m < 4; ++m)
    #pragma unroll
    for (int r = 0; r < 4; ++r) lsum[m][r] = 0.f;
  bf16x8 af[4][2];

  for (int kvt = 0; kvt < KV_ / 128; ++kvt) {
    const int cur = kvt & 1;
    if (kvt + 1 < KV_ / 128) {
      STAGE_KK(cur ^ 1, kvt + 1);
      wait_vmcnt<2>();
    } else {
      wait_vmcnt<0>();
    }
    barrier_raw();
    if (kvt == 0) {
      #pragma unroll
      for (int m = 0; m < 4; ++m) {
        const int rA = wm * 64 + m * 16 + lrow;
        af[m][0] = *(const bf16x8*)&Aq[rA * 64 + ((sub ^ lrow7) << 3)];
        af[m][1] = *(const bf16x8*)&Aq[rA * 64 + (((4 + sub) ^ lrow7) << 3)];
      }
    }
    bf16x8 bf[2][2];
    #pragma unroll
    for (int n = 0; n < 2; ++n) {
      const int rB = wn * 32 + n * 16 + lrow;
      bf[n][0] = *(const bf16x8*)&Kk[cur][rB * 64 + ((sub ^ lrow7) << 3)];
      bf[n][1] = *(const bf16x8*)&Kk[cur][rB * 64 + (((4 + sub) ^ lrow7) << 3)];
    }
    __builtin_amdgcn_s_setprio(1);
    #pragma unroll
    for (int m = 0; m < 4; ++m) {
      #pragma unroll
      for (int n = 0; n < 2; ++n) {
        f32x4 s = zero4;
        s = MFMA16(af[m][0], bf[n][0], s);
        s = MFMA16(af[m][1], bf[n][1], s);
        #pragma unroll
        for (int r = 0; r < 4; ++r) lsum[m][r] += EXP2F(s[r]);
      }
    }
    __builtin_amdgcn_s_setprio(0);
    barrier_raw();
  }
#undef STAGE_KK

  #pragma unroll
  for (int m = 0; m < 4; ++m)
    #pragma unroll
    for (int r = 0; r < 4; ++r) {
      #pragma unroll
      for (int off = 1; off < 16; off <<= 1)
        lsum[m][r] += __shfl_xor(lsum[m][r], off);
    }
  if (lrow == 0) {
    #pragma unroll
    for (int m = 0; m < 4; ++m)
      #pragma unroll
      for (int r = 0; r < 4; ++r)
        red[wn][wm * 64 + m * 16 + sub * 4 + r] = lsum[m][r];
  }
  __syncthreads();
  if (tid < 128) {
    const float s = red[0][tid] + red[1][tid] + red[2][tid] + red[3][tid];
    Linv[((size_t)b * H_ + h) * Q_ + qb + tid] = 1.0f / (s * (float)H_);
  }
}

// ---------------------------------------------------------------------------
// Kernel 6 (pass B): attn weights (round-13 form + XCD swizzle: a q-row
// chunk's 16 kv-blocks land on one XCD -> shared qp panel + kp panels hot).
// ---------------------------------------------------------------------------
__global__ __launch_bounds__(512) void k_attn_weights(
    const u16* __restrict__ qp, const u16* __restrict__ kp,
    const float* __restrict__ Linv, u16* __restrict__ attn)
{
  int bx = blockIdx.x, by = blockIdx.y;
  xcd_swz(bx, by);
  const int kv0 = bx * 128, qb = by * 128, b = blockIdx.z;
  __shared__ u16 As[2][128 * 64];
  __shared__ u16 Bs[2][128 * 64];
  __shared__ float linv_s[H_][128];
  const int tid = threadIdx.x, lane = tid & 63, w = tid >> 6;
  const int wm = w >> 2, wn = w & 3;
  const int lrow = lane & 15, sub = lane >> 4, lrow7 = lrow & 7;

  {
    const int hh = tid >> 5, i0 = (tid & 31) * 4;
    *reinterpret_cast<float4*>(&linv_s[hh][i0]) =
        *reinterpret_cast<const float4*>(&Linv[((size_t)b * H_ + hh) * Q_ + qb + i0]);
  }
  __syncthreads();

#define STAGE_AB(buf, hh)                                                     \
  {                                                                           \
    _Pragma("unroll")                                                         \
    for (int i = 0; i < 2; ++i) {                                             \
      const int c = i * 512 + tid, r = c >> 3, u = (c & 7) ^ (r & 7);         \
      gl_lds16(&qp[((size_t)b * Q_ + qb + r) * D_ + (hh) * 64 + u * 8],       \
               &As[buf][c * 8]);                                              \
      gl_lds16(&kp[((size_t)b * KV_ + kv0 + r) * D_ + (hh) * 64 + u * 8],     \
               &Bs[buf][c * 8]);                                              \
    }                                                                         \
  }

  const f32x4 zero4 = {0.f, 0.f, 0.f, 0.f};
  f32x4 acc[4][2];
  #pragma unroll
  for (int m = 0; m < 4; ++m)
    #pragma unroll
    for (int n = 0; n < 2; ++n) acc[m][n] = zero4;

  STAGE_AB(0, 0);
  for (int h = 0; h < H_; ++h) {
    const int cur = h & 1;
    if (h + 1 < H_) {
      STAGE_AB(cur ^ 1, h + 1);
      wait_vmcnt<4>();
    } else {
      wait_vmcnt<0>();
    }
    barrier_raw();
    bf16x8 af[4][2], bf[2][2];
    #pragma unroll
    for (int m = 0; m < 4; ++m) {
      const int rA = wm * 64 + m * 16 + lrow;
      af[m][0] = *(const bf16x8*)&As[cur][rA * 64 + ((sub ^ lrow7) << 3)];
      af[m][1] = *(const bf16x8*)&As[cur][rA * 64 + (((4 + sub) ^ lrow7) << 3)];
    }
    #pragma unroll
    for (int n = 0; n < 2; ++n) {
      const int rB = wn * 32 + n * 16 + lrow;
      bf[n][0] = *(const bf16x8*)&Bs[cur][rB * 64 + ((sub ^ lrow7) << 3)];
      bf[n][1] = *(const bf16x8*)&Bs[cur][rB * 64 + (((4 + sub) ^ lrow7) << 3)];
    }
    f32x4 lv[4];
    #pragma unroll
    for (int m = 0; m < 4; ++m)
      lv[m] = *(const f32x4*)&linv_s[h][wm * 64 + m * 16 + sub * 4];
    __builtin_amdgcn_s_setprio(1);
    #pragma unroll
    for (int m = 0; m < 4; ++m) {
      #pragma unroll
      for (int n = 0; n < 2; ++n) {
        f32x4 s = zero4;
        s = MFMA16(af[m][0], bf[n][0], s);
        s = MFMA16(af[m][1], bf[n][1], s);
        #pragma unroll
        for (int r = 0; r < 4; ++r)
          acc[m][n][r] += EXP2F(s[r]) * lv[m][r];
      }
    }
    __builtin_amdgcn_s_setprio(0);
    barrier_raw();
  }
#undef STAGE_AB

  #pragma unroll
  for (int m = 0; m < 4; ++m) {
    #pragma unroll
    for (int n = 0; n < 2; ++n) {
      const int gcol = kv0 + wn * 32 + n * 16 + lrow;
      #pragma unroll
      for (int r = 0; r < 4; ++r) {
        const int grow = qb + wm * 64 + m * 16 + sub * 4 + r;
        attn[((size_t)b * Q_ + grow) * KV_ + gcol] = f2bf(acc[m][n][r]);
      }
    }
  }
}

// ---------------------------------------------------------------------------
// Launch
// ---------------------------------------------------------------------------
extern "C" void kernel_launch(void* const* d_in, const int* in_sizes, int n_in,
                              void* d_out, int out_size, void* d_ws, size_t ws_size,
                              hipStream_t stream)
{
  (void)in_sizes; (void)n_in; (void)out_size; (void)ws_size;
  const float* query = (const float*)d_in[0];
  const float* key   = (const float*)d_in[1];
  const float* value = (const float*)d_in[2];
  const float* wqn   = (const float*)d_in[3];
  const float* wkn   = (const float*)d_in[4];
  const float* Wq    = (const float*)d_in[5];
  const float* Wk    = (const float*)d_in[6];
  const float* bq    = (const float*)d_in[7];
  const float* bk    = (const float*)d_in[8];
  float* out = (float*)d_out;

  // workspace layout (~46.7 MB; attn aliases the dead qn+kn region)
  char* ws = (char*)d_ws;
  u16* qn   = (u16*)(ws);                 //  8 MiB  (B*Q, D)  bf16
  u16* attn = (u16*)(ws);                 // 16 MiB  (B, Q, KV) bf16 — alias qn+kn
  u16* qp   = (u16*)(ws + 16777216);      //  8 MiB  (B*Q, D)  bf16
  u16* kp   = (u16*)(ws + 25165824);      //  8 MiB  (B*KV, D) bf16
  u16* Wqb  = (u16*)(ws + 33554432);      //  4 MiB  (2, D, D) bf16 (Wq|Wk adjacent)
  u16* vT   = (u16*)(ws + 37748736);      //  8 MiB  (B, D, KV) bf16
  float* Linv = (float*)(ws + 46137344);  // 256 KiB (B, H, Q) fp32
  float* biasbuf = (float*)(ws + 46399488); // 8 KiB (2, D) fp32
  u16* kn = qn + 4194304;

  // merged prep: rmsnorm (2048) + Wcast (1024) + bias (1) + V transpose (1024)
  k_prep<<<dim3(4097), dim3(256), 0, stream>>>(
      query, key, wqn, wkn, Wq, Wk, bq, bk, value, qn, kn, Wqb, biasbuf, vT);

  // batched projections: z=0 -> qp = (qn@Wq^T + bq)*QSCALE ; z=1 -> kp = kn@Wk^T + bk
  k_gemm_bt<128, 128, 2, 4, true, true>
      <<<dim3(D_ / 128, (B_ * Q_) / 128, 2), dim3(512), 0, stream>>>(
      qn, D_, 4194304, Wqb, D_, 1048576, qp, D_, 4194304, D_, biasbuf);

  k_attn_rowsum<<<dim3(Q_ / 128, H_, B_), dim3(512), 0, stream>>>(qp, kp, Linv);
  k_attn_weights<<<dim3(KV_ / 128, Q_ / 128, B_), dim3(512), 0, stream>>>(qp, kp, Linv, attn);

  // PV: 3-deep single-barrier pipeline, 128x64 tiles -> 512 blocks (2/CU)
  k_gemm_pv3<<<dim3(D_ / 64, Q_ / 128, B_), dim3(512), 0, stream>>>(
      attn, (long)Q_ * KV_, vT, (long)D_ * KV_, out, (long)Q_ * D_);
}

// Round 20
// 120.393 us; speedup vs baseline: 1.0498x; 1.0041x over previous
//
#include <hip/hip_runtime.h>

#define B_  2
#define Q_  2048
#define KV_ 2048
#define D_  1024
#define H_  16
#define DH_ 64

// 0.125 * log2(e): folded into qp so attention scores feed exp2 directly
#define QSCALE 0.18033688011112042f

using u16 = unsigned short;
using bf16x8 = __attribute__((ext_vector_type(8))) short;
using f32x4  = __attribute__((ext_vector_type(4))) float;

__device__ __forceinline__ u16 f2bf(float x) {
  unsigned u = __float_as_uint(x);
  u += 0x7fffu + ((u >> 16) & 1u);   // round-to-nearest-even
  return (u16)(u >> 16);
}

__device__ __forceinline__ void gl_lds16(const void* g, void* l) {
  __builtin_amdgcn_global_load_lds(
      (const __attribute__((address_space(1))) void*)g,
      (__attribute__((address_space(3))) void*)l, 16, 0, 0);
}

// Counted vmcnt wait. static_assert: an uncovered N must be a COMPILE error
// (round-14 lesson: a silent fall-through = no wait = LDS race).
template<int N> __device__ __forceinline__ void wait_vmcnt() {
  static_assert(N == 0 || N == 1 || N == 2 || N == 3 || N == 4 ||
                N == 6 || N == 8, "wait_vmcnt: unsupported N");
  if constexpr (N == 0)      asm volatile("s_waitcnt vmcnt(0)" ::: "memory");
  else if constexpr (N == 1) asm volatile("s_waitcnt vmcnt(1)" ::: "memory");
  else if constexpr (N == 2) asm volatile("s_waitcnt vmcnt(2)" ::: "memory");
  else if constexpr (N == 3) asm volatile("s_waitcnt vmcnt(3)" ::: "memory");
  else if constexpr (N == 4) asm volatile("s_waitcnt vmcnt(4)" ::: "memory");
  else if constexpr (N == 6) asm volatile("s_waitcnt vmcnt(6)" ::: "memory");
  else if constexpr (N == 8) asm volatile("s_waitcnt vmcnt(8)" ::: "memory");
}
__device__ __forceinline__ void barrier_raw() {
  asm volatile("" ::: "memory");
  __builtin_amdgcn_s_barrier();
  asm volatile("" ::: "memory");
}

// T1 XCD-aware bijective block swizzles (hardware dispatch: lin%8 -> XCD,
// validated by round-19's +3.5%). Each XCD gets a contiguous work chunk.
// Linear variant (proj, 8x32 grid): chunk = 4 consecutive by rows.
__device__ __forceinline__ void xcd_swz(int& bx, int& by) {
  const int gx = (int)gridDim.x;
  const int lin = by * gx + bx;                  // 0..255 within z-slice
  const int nl = (lin & 7) * 32 + (lin >> 3);    // bijective chunk remap
  bx = nl % gx;
  by = nl / gx;
}
// Tiled variant for 16x16 grids (weights/PV/rowsum): each XCD owns a
// 4(by) x 8(bx) tile -> balanced per-L2 working set (both operands hot):
// weights 3 MB, PV 4 MB, rowsum 1.5 MB vs 4.5-5 MB with the 2x16 slab.
__device__ __forceinline__ void xcd_swz16(int& bx, int& by) {
  const int lin = by * 16 + bx;
  const int c = lin & 7, pos = lin >> 3;         // XCD id, slot within chunk
  by = (c >> 1) * 4 + (pos >> 3);
  bx = (c & 1) * 8 + (pos & 7);
}

#define MFMA16(a, b, c) __builtin_amdgcn_mfma_f32_16x16x32_bf16((a), (b), (c), 0, 0, 0)
#define EXP2F(x) __builtin_amdgcn_exp2f(x)

// ---------------------------------------------------------------------------
// Kernel 1 (merged prep), grid 4097 (round-13 form)
// ---------------------------------------------------------------------------
__global__ __launch_bounds__(256) void k_prep(
    const float* __restrict__ q, const float* __restrict__ k,
    const float* __restrict__ wq, const float* __restrict__ wk,
    const float* __restrict__ Wq, const float* __restrict__ Wk,
    const float* __restrict__ bq, const float* __restrict__ bk,
    const float* __restrict__ v,
    u16* __restrict__ qn, u16* __restrict__ kn,
    u16* __restrict__ Wb, float* __restrict__ biasbuf,
    u16* __restrict__ vT)
{
  __shared__ char smem[64 * 72 * 2];
  const int bid = blockIdx.x, t = threadIdx.x;
  if (bid < 2048) {
    const int w = t >> 6, lane = t & 63;
    const int row = bid * 4 + w;
    const float* src; const float* wgt; u16* dst;
    if (row < B_ * Q_) {
      src = q + (size_t)row * D_; wgt = wq; dst = qn + (size_t)row * D_;
    } else {
      const int r2 = row - B_ * Q_;
      src = k + (size_t)r2 * D_; wgt = wk; dst = kn + (size_t)r2 * D_;
    }
    float4 v4[4];
    float ss = 0.f;
    #pragma unroll
    for (int i = 0; i < 4; ++i) {
      v4[i] = reinterpret_cast<const float4*>(src)[lane + 64 * i];
      ss += v4[i].x * v4[i].x + v4[i].y * v4[i].y
          + v4[i].z * v4[i].z + v4[i].w * v4[i].w;
    }
    #pragma unroll
    for (int off = 1; off < 64; off <<= 1) ss += __shfl_xor(ss, off);
    const float sc = rsqrtf(ss * (1.0f / D_) + 1.1920929e-07f);
    #pragma unroll
    for (int i = 0; i < 4; ++i) {
      const float4 wv = reinterpret_cast<const float4*>(wgt)[lane + 64 * i];
      ushort4 o;
      o.x = f2bf(v4[i].x * sc * wv.x);
      o.y = f2bf(v4[i].y * sc * wv.y);
      o.z = f2bf(v4[i].z * sc * wv.z);
      o.w = f2bf(v4[i].w * sc * wv.w);
      reinterpret_cast<ushort4*>(dst)[lane + 64 * i] = o;
    }
  } else if (bid < 3072) {
    const int pb = bid - 2048;
    #pragma unroll
    for (int rr = 0; rr < 2; ++rr) {
      const int i = pb * 512 + rr * 256 + t;
      const bool isK = i >= 262144;
      const int j = i & 262143;
      float4 vv = reinterpret_cast<const float4*>(isK ? Wk : Wq)[j];
      ushort4 o;
      o.x = f2bf(vv.x); o.y = f2bf(vv.y); o.z = f2bf(vv.z); o.w = f2bf(vv.w);
      reinterpret_cast<ushort4*>(Wb + (isK ? D_ * D_ : 0))[j] = o;
    }
  } else if (bid == 3072) {
    #pragma unroll
    for (int rr = 0; rr < 2; ++rr) {
      const int i = rr * 256 + t;
      float4 vv = (i < 256) ? reinterpret_cast<const float4*>(bq)[i]
                            : reinterpret_cast<const float4*>(bk)[i - 256];
      reinterpret_cast<float4*>(biasbuf)[i] = vv;
    }
  } else {
    const int tb = bid - 3073;
    const int kv0 = (tb & 31) * 64, d0 = ((tb >> 5) & 15) * 64, b = tb >> 9;
    u16 (*tile)[72] = (u16(*)[72])smem;
    #pragma unroll
    for (int i = 0; i < 16; ++i) {
      const int idx = i * 256 + t, r = idx >> 6, c = idx & 63;
      tile[r][c] = f2bf(v[((size_t)b * KV_ + kv0 + r) * D_ + d0 + c]);
    }
    __syncthreads();
    #pragma unroll
    for (int i = 0; i < 16; ++i) {
      const int idx = i * 256 + t, r = idx >> 6, c = idx & 63;
      vT[((size_t)b * D_ + d0 + r) * KV_ + kv0 + c] = tile[c][r];
    }
  }
}

// ---------------------------------------------------------------------------
// Kernel 4: C = A * B^T (+bias,*scale), bf16 in, fp32 accum. TM x TN tile,
// BK=64, 512 threads = 8 waves WM x WN, T2-swizzled LDS, 2-deep dbuf +
// counted-vmcnt pipeline + T1 XCD block swizzle. (used by the projections)
// ---------------------------------------------------------------------------
template<int TM, int TN, int WM, int WN, bool OUT_BF16, bool PROJ>
__global__ __launch_bounds__(512) void k_gemm_bt(
    const u16* __restrict__ A, int lda, long sA,
    const u16* __restrict__ Bm, int ldb, long sB,
    void* __restrict__ C, int ldc, long sC,
    int K, const float* __restrict__ bias)
{
  constexpr int RM = TM / WM / 16, RN = TN / WN / 16;
  constexpr int LA = TM / 64, LB = TN / 64;
  constexpr int NL = LA + LB;
  const int bb = blockIdx.z;
  const u16* Ab = A + (size_t)bb * sA;
  const u16* Bb = Bm + (size_t)bb * sB;
  int bx = blockIdx.x, by = blockIdx.y;
  xcd_swz(bx, by);
  const int row0 = by * TM, col0 = bx * TN;
  __shared__ u16 As[2][TM * 64];
  __shared__ u16 Bs[2][TN * 64];
  const int tid = threadIdx.x, lane = tid & 63;
  const int w = tid >> 6, wm = w / WN, wn = w % WN;
  const int lrow = lane & 15, sub = lane >> 4, lrow7 = lrow & 7;
  const f32x4 zero4 = {0.f, 0.f, 0.f, 0.f};
  f32x4 acc[RM][RN];
  #pragma unroll
  for (int m = 0; m < RM; ++m)
    #pragma unroll
    for (int n = 0; n < RN; ++n) acc[m][n] = zero4;

  const int nk = K >> 6;

#define GEMM_STAGE(buf, kt)                                                   \
  {                                                                           \
    const int k0 = (kt) << 6;                                                 \
    _Pragma("unroll")                                                         \
    for (int i = 0; i < LA; ++i) {                                            \
      const int c = i * 512 + tid, r = c >> 3, u = (c & 7) ^ (r & 7);         \
      gl_lds16(Ab + (size_t)(row0 + r) * lda + k0 + u * 8, &As[buf][c * 8]);  \
    }                                                                         \
    _Pragma("unroll")                                                         \
    for (int i = 0; i < LB; ++i) {                                            \
      const int c = i * 512 + tid, r = c >> 3, u = (c & 7) ^ (r & 7);         \
      gl_lds16(Bb + (size_t)(col0 + r) * ldb + k0 + u * 8, &Bs[buf][c * 8]);  \
    }                                                                         \
  }

  GEMM_STAGE(0, 0);
  int cur = 0;
  for (int kt = 0; kt < nk; ++kt) {
    if (kt + 1 < nk) {
      GEMM_STAGE(cur ^ 1, kt + 1);
      wait_vmcnt<NL>();                  // previous stage done; next in flight
    } else {
      wait_vmcnt<0>();
    }
    barrier_raw();                       // buf[cur] visible to all waves
    #pragma unroll
    for (int ks = 0; ks < 2; ++ks) {
      bf16x8 af[RM], bfr[RN];
      #pragma unroll
      for (int m = 0; m < RM; ++m) {
        const int rA = wm * (TM / WM) + m * 16 + lrow;
        af[m] = *(const bf16x8*)&As[cur][rA * 64 + ((((ks << 2) + sub) ^ lrow7) << 3)];
      }
      #pragma unroll
      for (int n = 0; n < RN; ++n) {
        const int rB = wn * (TN / WN) + n * 16 + lrow;
        bfr[n] = *(const bf16x8*)&Bs[cur][rB * 64 + ((((ks << 2) + sub) ^ lrow7) << 3)];
      }
      #pragma unroll
      for (int m = 0; m < RM; ++m)
        #pragma unroll
        for (int n = 0; n < RN; ++n)
          acc[m][n] = MFMA16(af[m], bfr[n], acc[m][n]);
    }
    barrier_raw();                       // all waves done reading buf[cur]
    cur ^= 1;
  }
#undef GEMM_STAGE

  const int crow = sub * 4, ccol = lane & 15;
  const float scl = (PROJ && bb == 0) ? QSCALE : 1.0f;
  #pragma unroll
  for (int m = 0; m < RM; ++m) {
    #pragma unroll
    for (int n = 0; n < RN; ++n) {
      const int gcol = col0 + wn * (TN / WN) + n * 16 + ccol;
      const float badd = PROJ ? bias[bb * 1024 + gcol] : 0.0f;
      #pragma unroll
      for (int r = 0; r < 4; ++r) {
        const int grow = row0 + wm * (TM / WM) + m * 16 + crow + r;
        const float val = (acc[m][n][r] + badd) * scl;
        if (OUT_BF16)
          ((u16*)C)[(size_t)bb * sC + (size_t)grow * ldc + gcol] = f2bf(val);
        else
          ((float*)C)[(size_t)bb * sC + (size_t)grow * ldc + gcol] = val;
      }
    }
  }
}

// ---------------------------------------------------------------------------
// Kernel 4b: PV GEMM, 3-deep rotation, ONE barrier per K-step + tiled XCD
// swizzle (4x8 chunk: 2 MB attn + 2 MB vT per L2).
// ---------------------------------------------------------------------------
__global__ __launch_bounds__(512) void k_gemm_pv3(
    const u16* __restrict__ A, long sA,      // attn: Q x KV rows, lda=KV
    const u16* __restrict__ Bm, long sB,     // vT:   D x KV rows, ldb=KV
    float* __restrict__ C, long sC)          // out:  Q x D, fp32
{
  const int bb = blockIdx.z;
  const u16* Ab = A + (size_t)bb * sA;
  const u16* Bb = Bm + (size_t)bb * sB;
  int bx = blockIdx.x, by = blockIdx.y;
  xcd_swz16(bx, by);
  const int row0 = by * 128, col0 = bx * 64;
  __shared__ u16 As3[3][128 * 64];           // 48 KB
  __shared__ u16 Bs3[3][64 * 64];            // 24 KB
  const int tid = threadIdx.x, lane = tid & 63;
  const int w = tid >> 6, wm = w >> 1, wn = w & 1;   // 4M x 2N
  const int lrow = lane & 15, sub = lane >> 4, lrow7 = lrow & 7;
  const f32x4 zero4 = {0.f, 0.f, 0.f, 0.f};
  f32x4 acc[2][2];
  #pragma unroll
  for (int m = 0; m < 2; ++m)
    #pragma unroll
    for (int n = 0; n < 2; ++n) acc[m][n] = zero4;

  const int nk = KV_ >> 6;                   // 32 K-tiles

#define PV_STAGE(buf, kt)                                                     \
  {                                                                           \
    const int k0 = (kt) << 6;                                                 \
    _Pragma("unroll")                                                         \
    for (int i = 0; i < 2; ++i) {                                             \
      const int c = i * 512 + tid, r = c >> 3, u = (c & 7) ^ (r & 7);         \
      gl_lds16(Ab + (size_t)(row0 + r) * KV_ + k0 + u * 8, &As3[buf][c * 8]); \
    }                                                                         \
    {                                                                         \
      const int c = tid, r = c >> 3, u = (c & 7) ^ (r & 7);                   \
      gl_lds16(Bb + (size_t)(col0 + r) * KV_ + k0 + u * 8, &Bs3[buf][c * 8]); \
    }                                                                         \
  }

  PV_STAGE(0, 0);
  PV_STAGE(1, 1);
  for (int kt = 0; kt < nk; ++kt) {
    const int cb = kt % 3;
    if (kt + 1 < nk) wait_vmcnt<3>();        // tile kt landed; kt+1 in flight
    else             wait_vmcnt<0>();
    barrier_raw();                           // orders vs compute(kt-1) too
    if (kt + 2 < nk) PV_STAGE((kt + 2) % 3, kt + 2);
    #pragma unroll
    for (int ks = 0; ks < 2; ++ks) {
      bf16x8 af[2], bfr[2];
      #pragma unroll
      for (int m = 0; m < 2; ++m) {
        const int rA = wm * 32 + m * 16 + lrow;
        af[m] = *(const bf16x8*)&As3[cb][rA * 64 + ((((ks << 2) + sub) ^ lrow7) << 3)];
      }
      #pragma unroll
      for (int n = 0; n < 2; ++n) {
        const int rB = wn * 32 + n * 16 + lrow;
        bfr[n] = *(const bf16x8*)&Bs3[cb][rB * 64 + ((((ks << 2) + sub) ^ lrow7) << 3)];
      }
      #pragma unroll
      for (int m = 0; m < 2; ++m)
        #pragma unroll
        for (int n = 0; n < 2; ++n)
          acc[m][n] = MFMA16(af[m], bfr[n], acc[m][n]);
    }
  }
#undef PV_STAGE

  const int crow = sub * 4, ccol = lane & 15;
  #pragma unroll
  for (int m = 0; m < 2; ++m) {
    #pragma unroll
    for (int n = 0; n < 2; ++n) {
      const int gcol = col0 + wn * 32 + n * 16 + ccol;
      #pragma unroll
      for (int r = 0; r < 4; ++r) {
        const int grow = row0 + wm * 32 + m * 16 + crow + r;
        C[(size_t)bb * sC + (size_t)grow * D_ + gcol] = acc[m][n][r];
      }
    }
  }
}

// ---------------------------------------------------------------------------
// Kernel 5 (pass A): Linv[b,h,i] = 1 / (H * sum_j 2^s(i,j))   (qp pre-scaled)
// block = (128 q-rows, head, batch), 8 waves 2x4 (64q x 32kv). Aq staged
// once; K 128-tiles 2-deep dbuf + counted vmcnt + tiled XCD swizzle.
// ---------------------------------------------------------------------------
__global__ __launch_bounds__(512) void k_attn_rowsum(
    const u16* __restrict__ qp, const u16* __restrict__ kp,
    float* __restrict__ Linv)
{
  int bx = blockIdx.x, by = blockIdx.y;
  xcd_swz16(bx, by);
  const int qb = bx * 128, h = by, b = blockIdx.z;
  __shared__ u16 Aq[128 * 64];
  __shared__ u16 Kk[2][128 * 64];
  __shared__ float red[4][128];
  const int tid = threadIdx.x, lane = tid & 63, w = tid >> 6;
  const int wm = w >> 2, wn = w & 3;
  const int lrow = lane & 15, sub = lane >> 4, lrow7 = lrow & 7;

  #pragma unroll
  for (int i = 0; i < 2; ++i) {
    const int c = i * 512 + tid, r = c >> 3, u = (c & 7) ^ (r & 7);
    gl_lds16(&qp[((size_t)b * Q_ + qb + r) * D_ + h * 64 + u * 8], &Aq[c * 8]);
  }

#define STAGE_KK(buf, kvt)                                                    \
  {                                                                           \
    _Pragma("unroll")                                                         \
    for (int i = 0; i < 2; ++i) {                                             \
      const int c = i * 512 + tid, r = c >> 3, u = (c & 7) ^ (r & 7);         \
      gl_lds16(&kp[((size_t)b * KV_ + (kvt) * 128 + r) * D_ + h * 64 + u * 8],\
               &Kk[buf][c * 8]);                                              \
    }                                                                         \
  }

  STAGE_KK(0, 0);
  const f32x4 zero4 = {0.f, 0.f, 0.f, 0.f};
  float lsum[4][4];
  #pragma unroll
  for (int m = 0; m < 4; ++m)
    #pragma unroll
    for (int r = 0; r < 4; ++r) lsum[m][r] = 0.f;
  bf16x8 af[4][2];

  for (int kvt = 0; kvt < KV_ / 128; ++kvt) {
    const int cur = kvt & 1;
    if (kvt + 1 < KV_ / 128) {
      STAGE_KK(cur ^ 1, kvt + 1);
      wait_vmcnt<2>();
    } else {
      wait_vmcnt<0>();
    }
    barrier_raw();
    if (kvt == 0) {
      #pragma unroll
      for (int m = 0; m < 4; ++m) {
        const int rA = wm * 64 + m * 16 + lrow;
        af[m][0] = *(const bf16x8*)&Aq[rA * 64 + ((sub ^ lrow7) << 3)];
        af[m][1] = *(const bf16x8*)&Aq[rA * 64 + (((4 + sub) ^ lrow7) << 3)];
      }
    }
    bf16x8 bf[2][2];
    #pragma unroll
    for (int n = 0; n < 2; ++n) {
      const int rB = wn * 32 + n * 16 + lrow;
      bf[n][0] = *(const bf16x8*)&Kk[cur][rB * 64 + ((sub ^ lrow7) << 3)];
      bf[n][1] = *(const bf16x8*)&Kk[cur][rB * 64 + (((4 + sub) ^ lrow7) << 3)];
    }
    __builtin_amdgcn_s_setprio(1);
    #pragma unroll
    for (int m = 0; m < 4; ++m) {
      #pragma unroll
      for (int n = 0; n < 2; ++n) {
        f32x4 s = zero4;
        s = MFMA16(af[m][0], bf[n][0], s);
        s = MFMA16(af[m][1], bf[n][1], s);
        #pragma unroll
        for (int r = 0; r < 4; ++r) lsum[m][r] += EXP2F(s[r]);
      }
    }
    __builtin_amdgcn_s_setprio(0);
    barrier_raw();
  }
#undef STAGE_KK

  #pragma unroll
  for (int m = 0; m < 4; ++m)
    #pragma unroll
    for (int r = 0; r < 4; ++r) {
      #pragma unroll
      for (int off = 1; off < 16; off <<= 1)
        lsum[m][r] += __shfl_xor(lsum[m][r], off);
    }
  if (lrow == 0) {
    #pragma unroll
    for (int m = 0; m < 4; ++m)
      #pragma unroll
      for (int r = 0; r < 4; ++r)
        red[wn][wm * 64 + m * 16 + sub * 4 + r] = lsum[m][r];
  }
  __syncthreads();
  if (tid < 128) {
    const float s = red[0][tid] + red[1][tid] + red[2][tid] + red[3][tid];
    Linv[((size_t)b * H_ + h) * Q_ + qb + tid] = 1.0f / (s * (float)H_);
  }
}

// ---------------------------------------------------------------------------
// Kernel 6 (pass B): attn weights (round-13 form + tiled XCD swizzle:
// each XCD owns 4 q-chunks x 8 kv-chunks -> 1 MB qp + 2 MB kp per L2).
// ---------------------------------------------------------------------------
__global__ __launch_bounds__(512) void k_attn_weights(
    const u16* __restrict__ qp, const u16* __restrict__ kp,
    const float* __restrict__ Linv, u16* __restrict__ attn)
{
  int bx = blockIdx.x, by = blockIdx.y;
  xcd_swz16(bx, by);
  const int kv0 = bx * 128, qb = by * 128, b = blockIdx.z;
  __shared__ u16 As[2][128 * 64];
  __shared__ u16 Bs[2][128 * 64];
  __shared__ float linv_s[H_][128];
  const int tid = threadIdx.x, lane = tid & 63, w = tid >> 6;
  const int wm = w >> 2, wn = w & 3;
  const int lrow = lane & 15, sub = lane >> 4, lrow7 = lrow & 7;

  {
    const int hh = tid >> 5, i0 = (tid & 31) * 4;
    *reinterpret_cast<float4*>(&linv_s[hh][i0]) =
        *reinterpret_cast<const float4*>(&Linv[((size_t)b * H_ + hh) * Q_ + qb + i0]);
  }
  __syncthreads();

#define STAGE_AB(buf, hh)                                                     \
  {                                                                           \
    _Pragma("unroll")                                                         \
    for (int i = 0; i < 2; ++i) {                                             \
      const int c = i * 512 + tid, r = c >> 3, u = (c & 7) ^ (r & 7);         \
      gl_lds16(&qp[((size_t)b * Q_ + qb + r) * D_ + (hh) * 64 + u * 8],       \
               &As[buf][c * 8]);                                              \
      gl_lds16(&kp[((size_t)b * KV_ + kv0 + r) * D_ + (hh) * 64 + u * 8],     \
               &Bs[buf][c * 8]);                                              \
    }                                                                         \
  }

  const f32x4 zero4 = {0.f, 0.f, 0.f, 0.f};
  f32x4 acc[4][2];
  #pragma unroll
  for (int m = 0; m < 4; ++m)
    #pragma unroll
    for (int n = 0; n < 2; ++n) acc[m][n] = zero4;

  STAGE_AB(0, 0);
  for (int h = 0; h < H_; ++h) {
    const int cur = h & 1;
    if (h + 1 < H_) {
      STAGE_AB(cur ^ 1, h + 1);
      wait_vmcnt<4>();
    } else {
      wait_vmcnt<0>();
    }
    barrier_raw();
    bf16x8 af[4][2], bf[2][2];
    #pragma unroll
    for (int m = 0; m < 4; ++m) {
      const int rA = wm * 64 + m * 16 + lrow;
      af[m][0] = *(const bf16x8*)&As[cur][rA * 64 + ((sub ^ lrow7) << 3)];
      af[m][1] = *(const bf16x8*)&As[cur][rA * 64 + (((4 + sub) ^ lrow7) << 3)];
    }
    #pragma unroll
    for (int n = 0; n < 2; ++n) {
      const int rB = wn * 32 + n * 16 + lrow;
      bf[n][0] = *(const bf16x8*)&Bs[cur][rB * 64 + ((sub ^ lrow7) << 3)];
      bf[n][1] = *(const bf16x8*)&Bs[cur][rB * 64 + (((4 + sub) ^ lrow7) << 3)];
    }
    f32x4 lv[4];
    #pragma unroll
    for (int m = 0; m < 4; ++m)
      lv[m] = *(const f32x4*)&linv_s[h][wm * 64 + m * 16 + sub * 4];
    __builtin_amdgcn_s_setprio(1);
    #pragma unroll
    for (int m = 0; m < 4; ++m) {
      #pragma unroll
      for (int n = 0; n < 2; ++n) {
        f32x4 s = zero4;
        s = MFMA16(af[m][0], bf[n][0], s);
        s = MFMA16(af[m][1], bf[n][1], s);
        #pragma unroll
        for (int r = 0; r < 4; ++r)
          acc[m][n][r] += EXP2F(s[r]) * lv[m][r];
      }
    }
    __builtin_amdgcn_s_setprio(0);
    barrier_raw();
  }
#undef STAGE_AB

  #pragma unroll
  for (int m = 0; m < 4; ++m) {
    #pragma unroll
    for (int n = 0; n < 2; ++n) {
      const int gcol = kv0 + wn * 32 + n * 16 + lrow;
      #pragma unroll
      for (int r = 0; r < 4; ++r) {
        const int grow = qb + wm * 64 + m * 16 + sub * 4 + r;
        attn[((size_t)b * Q_ + grow) * KV_ + gcol] = f2bf(acc[m][n][r]);
      }
    }
  }
}

// ---------------------------------------------------------------------------
// Launch
// ---------------------------------------------------------------------------
extern "C" void kernel_launch(void* const* d_in, const int* in_sizes, int n_in,
                              void* d_out, int out_size, void* d_ws, size_t ws_size,
                              hipStream_t stream)
{
  (void)in_sizes; (void)n_in; (void)out_size; (void)ws_size;
  const float* query = (const float*)d_in[0];
  const float* key   = (const float*)d_in[1];
  const float* value = (const float*)d_in[2];
  const float* wqn   = (const float*)d_in[3];
  const float* wkn   = (const float*)d_in[4];
  const float* Wq    = (const float*)d_in[5];
  const float* Wk    = (const float*)d_in[6];
  const float* bq    = (const float*)d_in[7];
  const float* bk    = (const float*)d_in[8];
  float* out = (float*)d_out;

  // workspace layout (~46.7 MB; attn aliases the dead qn+kn region)
  char* ws = (char*)d_ws;
  u16* qn   = (u16*)(ws);                 //  8 MiB  (B*Q, D)  bf16
  u16* attn = (u16*)(ws);                 // 16 MiB  (B, Q, KV) bf16 — alias qn+kn
  u16* qp   = (u16*)(ws + 16777216);      //  8 MiB  (B*Q, D)  bf16
  u16* kp   = (u16*)(ws + 25165824);      //  8 MiB  (B*KV, D) bf16
  u16* Wqb  = (u16*)(ws + 33554432);      //  4 MiB  (2, D, D) bf16 (Wq|Wk adjacent)
  u16* vT   = (u16*)(ws + 37748736);      //  8 MiB  (B, D, KV) bf16
  float* Linv = (float*)(ws + 46137344);  // 256 KiB (B, H, Q) fp32
  float* biasbuf = (float*)(ws + 46399488); // 8 KiB (2, D) fp32
  u16* kn = qn + 4194304;

  // merged prep: rmsnorm (2048) + Wcast (1024) + bias (1) + V transpose (1024)
  k_prep<<<dim3(4097), dim3(256), 0, stream>>>(
      query, key, wqn, wkn, Wq, Wk, bq, bk, value, qn, kn, Wqb, biasbuf, vT);

  // batched projections: z=0 -> qp = (qn@Wq^T + bq)*QSCALE ; z=1 -> kp = kn@Wk^T + bk
  k_gemm_bt<128, 128, 2, 4, true, true>
      <<<dim3(D_ / 128, (B_ * Q_) / 128, 2), dim3(512), 0, stream>>>(
      qn, D_, 4194304, Wqb, D_, 1048576, qp, D_, 4194304, D_, biasbuf);

  k_attn_rowsum<<<dim3(Q_ / 128, H_, B_), dim3(512), 0, stream>>>(qp, kp, Linv);
  k_attn_weights<<<dim3(KV_ / 128, Q_ / 128, B_), dim3(512), 0, stream>>>(qp, kp, Linv, attn);

  // PV: 3-deep single-barrier pipeline, 128x64 tiles -> 512 blocks (2/CU)
  k_gemm_pv3<<<dim3(D_ / 64, Q_ / 128, B_), dim3(512), 0, stream>>>(
      attn, (long)Q_ * KV_, vT, (long)D_ * KV_, out, (long)Q_ * D_);
}